// Round 11
// baseline (2028.170 us; speedup 1.0000x reference)
//
#include <hip/hip_runtime.h>

// PointNetSAModule on MI355X (gfx950).
// B=16, N=8192, CIN=64, S=1024, K=32, radius=0.2, MLP 67->64->64->128, eps=1e-5.
// Inputs/outputs float32 (proven R4). ws footprint = 1,087,488 B (< proven 1,088,512).
//
// R10 -> R11:
//  * fps (VALU-bound at 99% of its 16-CU ceiling): value-only DPP max reduction
//    (no per-point index bookkeeping), index recovered by bit-exact value match
//    + LDS atomicMin (smallest global index = numpy first-argmax).
//  * mlp_pass: XCD-affinity block swizzle (blk&7 -> 2 batches/XCD, 4MB = L2size);
//    R10 FETCH=150MB/pass vs 32MB feat tensor = cross-XCD L2 thrash.

typedef unsigned short u16;
typedef unsigned int   u32;
typedef unsigned long long u64;

#define NB    16
#define NPTS  8192
#define CINF  64
#define NS    1024
#define KK    32
#define NSAMP (NB*NS*KK)   // 524288

typedef _Float16 h2v   __attribute__((ext_vector_type(2)));
typedef _Float16 f16x8 __attribute__((ext_vector_type(8)));
typedef float    f32x4 __attribute__((ext_vector_type(4)));

static __device__ __forceinline__ h2v asH2(u32 x){ union{u32 u; h2v h;} v; v.u=x; return v.h; }
static __device__ __forceinline__ u32 asU32(h2v h){ union{u32 u; h2v h;} v; v.h=h; return v.u; }
static __device__ __forceinline__ u32 packh(float lo, float hi){
  union{ _Float16 h[2]; u32 u; } v;
  v.h[0]=(_Float16)lo; v.h[1]=(_Float16)hi; return v.u;
}
static __device__ __forceinline__ f32x4 zero4(){ f32x4 z; z[0]=0.f;z[1]=0.f;z[2]=0.f;z[3]=0.f; return z; }
static __device__ __forceinline__ f16x8 zero8h(){
  f16x8 z;
  #pragma unroll
  for (int i=0;i<8;i++) z[i]=(_Float16)0.f;
  return z;
}

// exact-order d^2, matching numpy f32: (dx*dx + dy*dy) + dz*dz, no FMA contraction
static __device__ __forceinline__ float d2_exact(float ax,float ay,float az,float bx,float by,float bz){
  float dx=__fsub_rn(ax,bx), dy=__fsub_rn(ay,by), dz=__fsub_rn(az,bz);
  return __fadd_rn(__fadd_rn(__fmul_rn(dx,dx),__fmul_rn(dy,dy)),__fmul_rn(dz,dz));
}

// one DPP fmax level (VALU pipe; masked rows keep current value)
template<int CTRL, int RMASK>
static __device__ __forceinline__ float dppfmax(float v){
  int o = __builtin_amdgcn_update_dpp(__float_as_int(v), __float_as_int(v),
                                      CTRL, RMASK, 0xf, false);
  return fmaxf(v, __int_as_float(o));
}

// ---------------------------------------------------------------- prep ----
// A-operand fragments in exact MFMA lane order: entry ((tc*2+kc)*64+lane)*4+d,
// lane m=lane&15 (channel row), q=lane>>4, k=kc*32+q*8+{2d,2d+1}.
__global__ void prep_kernel(const float* __restrict__ W0, const float* __restrict__ W1,
                            const float* __restrict__ W2,
                            u32* __restrict__ Wf1, u32* __restrict__ Wf2, u32* __restrict__ Wf3,
                            float* __restrict__ stats)
{
  const int t = threadIdx.x;
  for (int i=t;i<768;i+=256) stats[i]=0.f;
  for (int i=t;i<2048;i+=256){           // L1: 4 tiles x 2 chunks (feat cols only)
    int d=i&3, lane=(i>>2)&63, kc=(i>>8)&1, tc=i>>9;
    int row=tc*16+(lane&15), k0=kc*32+(lane>>4)*8+2*d;
    Wf1[i]=packh(W0[row*67+3+k0], W0[row*67+4+k0]);
  }
  for (int i=t;i<2048;i+=256){           // L2
    int d=i&3, lane=(i>>2)&63, kc=(i>>8)&1, tc=i>>9;
    int row=tc*16+(lane&15), k0=kc*32+(lane>>4)*8+2*d;
    Wf2[i]=packh(W1[row*64+k0], W1[row*64+k0+1]);
  }
  for (int i=t;i<4096;i+=256){           // L3
    int d=i&3, lane=(i>>2)&63, kc=(i>>8)&1, tc=i>>9;
    int row=tc*16+(lane&15), k0=kc*32+(lane>>4)*8+2*d;
    Wf3[i]=packh(W2[row*64+k0], W2[row*64+k0+1]);
  }
}

// ----------------------------------------------------------------- FPS ----
// one block per batch; 1024 threads, 8 consecutive points/thread in LDS.
// Per step: value-only max (8x fmax into bv -> 6 DPP wave levels -> 16 LDS
// slots -> 4 DPP levels -> readfirstlane), then index recovered by matching
// d[i]==winner (bit-exact) with descending-i select + LDS atomicMin.
__global__ __launch_bounds__(1024,1) void fps_kernel(const float* __restrict__ xyz,
    float* __restrict__ out_xyz)
{
  __shared__ float sc[1024*28];            // 114,688 B
  __shared__ float s_v[2][16];
  __shared__ int   s_widx[2];
  const int b = blockIdx.x, t = threadIdx.x;
  const float* xb = xyz + (size_t)b*3*NPTS;
  const int tb = t*28;
  #pragma unroll
  for (int i=0;i<8;i++){
    const int idx = 8*t + i;
    sc[tb+i]    = xb[idx];
    sc[tb+8+i]  = xb[NPTS+idx];
    sc[tb+16+i] = xb[2*NPTS+idx];
  }
  float d[8];
  #pragma unroll
  for (int i=0;i<8;i++) d[i]=__builtin_inff();
  if (t==0){ s_widx[0]=0x7fffffff; s_widx[1]=0x7fffffff; }
  __syncthreads();
  float cx = xb[0], cy = xb[NPTS], cz = xb[2*NPTS];   // initial center = point 0
  const int lane = t & 63, wv = t >> 6, l16 = lane & 15;
  for (int step=0; step<NS; step++){
    if (t==0){
      out_xyz[(size_t)(b*3+0)*NS+step]=cx;
      out_xyz[(size_t)(b*3+1)*NS+step]=cy;
      out_xyz[(size_t)(b*3+2)*NS+step]=cz;
    }
    if (step==NS-1) break;
    float4 X0 = *(const float4*)&sc[tb];
    float4 X1 = *(const float4*)&sc[tb+4];
    float4 Y0 = *(const float4*)&sc[tb+8];
    float4 Y1 = *(const float4*)&sc[tb+12];
    float4 Z0 = *(const float4*)&sc[tb+16];
    float4 Z1 = *(const float4*)&sc[tb+20];
    float bv = -1.f;
#define UPD(i, PX, PY, PZ) { \
    float d2 = d2_exact(PX,PY,PZ, cx,cy,cz); \
    float nd = fminf(d[i], d2); d[i]=nd; \
    bv = fmaxf(bv, nd); }
    UPD(0, X0.x, Y0.x, Z0.x)  UPD(1, X0.y, Y0.y, Z0.y)
    UPD(2, X0.z, Y0.z, Z0.z)  UPD(3, X0.w, Y0.w, Z0.w)
    UPD(4, X1.x, Y1.x, Z1.x)  UPD(5, X1.y, Y1.y, Z1.y)
    UPD(6, X1.z, Y1.z, Z1.z)  UPD(7, X1.w, Y1.w, Z1.w)
#undef UPD
    bv = dppfmax<0xB1,0xf>(bv);          // quad_perm xor1
    bv = dppfmax<0x4E,0xf>(bv);          // quad_perm xor2
    bv = dppfmax<0x141,0xf>(bv);         // row_half_mirror
    bv = dppfmax<0x140,0xf>(bv);         // row_mirror
    bv = dppfmax<0x142,0xa>(bv);         // row_bcast15 (rows 1,3)
    bv = dppfmax<0x143,0xc>(bv);         // row_bcast31 (rows 2,3) -> lane 63
    const int p = step&1;
    if (lane==63) s_v[p][wv]=bv;
    __syncthreads();
    float v2 = s_v[p][l16];
    v2 = dppfmax<0xB1,0xf>(v2);
    v2 = dppfmax<0x4E,0xf>(v2);
    v2 = dppfmax<0x141,0xf>(v2);
    v2 = dppfmax<0x140,0xf>(v2);         // all lanes: max of their 16-group
    const float wval = __int_as_float(__builtin_amdgcn_readfirstlane(__float_as_int(v2)));
    if (t==0) s_widx[1-p] = 0x7fffffff;  // reset other buffer for next step
    int cand = 0x7fffffff;
    #pragma unroll
    for (int i=7;i>=0;i--) cand = (d[i]==wval) ? (8*t+i) : cand;  // smallest i wins
    if (cand != 0x7fffffff) atomicMin(&s_widx[p], cand);
    __syncthreads();
    const int widx = s_widx[p];
    const int wb2 = (widx>>3)*28, wi = widx&7;
    cx = sc[wb2+wi]; cy = sc[wb2+8+wi]; cz = sc[wb2+16+wi];
  }
}

// ---------------------------------------------------------- ball query ----
__global__ __launch_bounds__(256) void ballq_kernel(const float* __restrict__ xyz,
    const float* __restrict__ out_xyz, u16* __restrict__ gidx)
{
  const int gid = blockIdx.x*4 + (threadIdx.x>>6);
  const int lane = threadIdx.x & 63;
  const int b = gid >> 10, s = gid & (NS-1);
  const float* xb = xyz + (size_t)b*3*NPTS;
  const float cx = out_xyz[(size_t)(b*3+0)*NS+s];
  const float cy = out_xyz[(size_t)(b*3+1)*NS+s];
  const float cz = out_xyz[(size_t)(b*3+2)*NS+s];
  u16* out = gidx + (size_t)gid*KK;
  int cnt=0, first=-1;
  for (int base=0; base<NPTS; base+=64){
    const int pidx = base + lane;
    float d2 = d2_exact(cx,cy,cz, xb[pidx], xb[NPTS+pidx], xb[2*NPTS+pidx]);
    bool within = d2 < 0.04f;
    unsigned long long m = __ballot(within);
    if (m){
      if (first<0) first = base + (__ffsll(m)-1);
      int pos = cnt + (int)__popcll(m & ((1ull<<lane)-1ull));
      if (within && pos<KK) out[pos]=(u16)pidx;
      cnt += (int)__popcll(m);
      if (cnt>=KK) break;
    }
  }
  if (first<0) first=0;
  for (int posi = cnt + lane; posi < KK; posi += 64) out[posi]=(u16)first;
}

// --------------------------------------------------------------- MLP -----
// STAGE 0: stats(y1) | 1: stats(y2) | 2: stats(y3) + (max,min) over K -> out.
// Block = 256 thr = 4 waves; 4 chunks x 64 samples; wave owns 16 samples.
// XCD-affinity swizzle: slot=blk&7 -> batches {2slot, 2slot+1} (4MB feat = L2).
#define MFMA16(A,B,C) __builtin_amdgcn_mfma_f32_16x16x32_f16(A,B,C,0,0,0)

template<int STAGE>
__global__ __launch_bounds__(256,2) void mlp_pass(
    const float* __restrict__ xyz, const float* __restrict__ feat,
    const float* __restrict__ out_xyz, const u16* __restrict__ gidx,
    const u32* __restrict__ Wf1, const u32* __restrict__ Wf2, const u32* __restrict__ Wf3,
    const float* __restrict__ W0raw,
    const float* __restrict__ affine, float* __restrict__ stats, u32* __restrict__ outMM)
{
  constexpr int TCO = (STAGE==2)?128:64;
  __shared__ alignas(16) u32 Xs[64*48];          // 12 KB
  __shared__ float bins[2*TCO];
  __shared__ u32 mm[(STAGE==2)? 2*4*128 : 4];    // double-buffered cross-wave panel

  const int t = threadIdx.x;
  const int lane = t&63, w = t>>6, n = lane&15, q = lane>>4;
  const int j = t>>2, q4 = t&3;                  // gather role: sample j, quarter q4
  const int colbase = (w*16+n)*48;
  // XCD-affinity block swizzle (bijective on [0,2048))
  const int u_   = blockIdx.x;
  const int slot = u_ & 7, rr = u_ >> 3;
  const int bb   = slot*2 + (rr>>7);
  const int inner= rr & 127;
  if (t < 2*TCO) bins[t]=0.f;
  __syncthreads();                               // bins zero visible to all

  #pragma unroll 1
  for (int ch=0; ch<4; ch++){
    const int ss = (bb*128 + inner)*256 + ch*64 + j;   // flat (b,s,k)
    const int b = ss >> 15;
    const int s = (ss >> 5) & (NS-1);
    const int g = ((int)gidx[ss]) & (NPTS-1);
    // ---- gather: 4 threads per sample, 16 feats each; q4==3 adds dxyz ----
    {
      const float* fb = feat + (size_t)b*CINF*NPTS + g;
      u32* Xrow = &Xs[j*48];
      #pragma unroll
      for (int m2=0;m2<8;m2++){
        float a0 = fb[(size_t)(16*q4+2*m2)*NPTS];
        float a1 = fb[(size_t)(16*q4+2*m2+1)*NPTS];
        Xrow[8*q4+m2] = packh(a0,a1);
      }
      if (q4==3){
        const float* xb = xyz + (size_t)b*3*NPTS;
        float dx=__fsub_rn(xb[g],        out_xyz[(size_t)(b*3+0)*NS+s]);
        float dy=__fsub_rn(xb[NPTS+g],   out_xyz[(size_t)(b*3+1)*NS+s]);
        float dz=__fsub_rn(xb[2*NPTS+g], out_xyz[(size_t)(b*3+2)*NS+s]);
        Xrow[32]=packh(dx,dy); Xrow[33]=packh(dz,0.f);
      }
      #pragma unroll
      for (int i=34+q4;i<48;i+=4) Xrow[i]=0;
    }
    // ---- layer 1: Y1(64ch x 16smp) = W0 * X ----
    f32x4 acc[4];
    #pragma unroll
    for (int tc=0;tc<4;tc++) acc[tc]=zero4();
    #pragma unroll
    for (int kc=0;kc<2;kc++){
      f16x8 Bf = *(const f16x8*)&Xs[colbase + kc*16 + q*4];
      #pragma unroll
      for (int tc=0;tc<4;tc++){
        f16x8 Af = *(const f16x8*)&Wf1[((tc*2+kc)*64+lane)*4];
        acc[tc] = MFMA16(Af,Bf,acc[tc]);
      }
    }
    {  // xyz chunk: only q==0 of A nonzero (W0 cols 0..2), B dwords 32..47
      f16x8 Bf = *(const f16x8*)&Xs[colbase + 32 + q*4];
      #pragma unroll
      for (int tc=0;tc<4;tc++){
        f16x8 Af = zero8h();
        if (q==0){
          const int row = tc*16+n;
          Af[0]=(_Float16)W0raw[row*67+0];
          Af[1]=(_Float16)W0raw[row*67+1];
          Af[2]=(_Float16)W0raw[row*67+2];
        }
        acc[tc] = MFMA16(Af,Bf,acc[tc]);
      }
    }

    if constexpr (STAGE==0){
      #pragma unroll
      for (int tc=0;tc<4;tc++){
        #pragma unroll
        for (int r=0;r<4;r++){
          float s1=acc[tc][r], s2=__fmul_rn(s1,s1);
          #pragma unroll
          for (int off=1;off<16;off<<=1){ s1+=__shfl_xor(s1,off); s2+=__shfl_xor(s2,off); }
          if (n==0){ const int c=tc*16+q*4+r;
            atomicAdd(&bins[c], s1); atomicAdd(&bins[TCO+c], s2); }
        }
      }
    } else {
      // affine L1 + relu -> f16 -> X panel
      #pragma unroll
      for (int tc=0;tc<4;tc++){
        const f32x4 sc4 = *(const f32x4*)&affine[tc*16+q*4];
        const f32x4 sh4 = *(const f32x4*)&affine[128+tc*16+q*4];
        Xs[colbase + tc*8+q*2]   = packh(fmaxf(fmaf(acc[tc][0],sc4[0],sh4[0]),0.f),
                                         fmaxf(fmaf(acc[tc][1],sc4[1],sh4[1]),0.f));
        Xs[colbase + tc*8+q*2+1] = packh(fmaxf(fmaf(acc[tc][2],sc4[2],sh4[2]),0.f),
                                         fmaxf(fmaf(acc[tc][3],sc4[3],sh4[3]),0.f));
      }
      // ---- layer 2 ----
      f32x4 acc2[4];
      #pragma unroll
      for (int tc=0;tc<4;tc++) acc2[tc]=zero4();
      #pragma unroll
      for (int kc=0;kc<2;kc++){
        f16x8 Bf = *(const f16x8*)&Xs[colbase + kc*16 + q*4];
        #pragma unroll
        for (int tc=0;tc<4;tc++){
          f16x8 Af = *(const f16x8*)&Wf2[((tc*2+kc)*64+lane)*4];
          acc2[tc] = MFMA16(Af,Bf,acc2[tc]);
        }
      }
      if constexpr (STAGE==1){
        #pragma unroll
        for (int tc=0;tc<4;tc++){
          #pragma unroll
          for (int r=0;r<4;r++){
            float s1=acc2[tc][r], s2=__fmul_rn(s1,s1);
            #pragma unroll
            for (int off=1;off<16;off<<=1){ s1+=__shfl_xor(s1,off); s2+=__shfl_xor(s2,off); }
            if (n==0){ const int c=tc*16+q*4+r;
              atomicAdd(&bins[c], s1); atomicAdd(&bins[TCO+c], s2); }
          }
        }
      } else {
        #pragma unroll
        for (int tc=0;tc<4;tc++){
          const f32x4 sc4 = *(const f32x4*)&affine[256+tc*16+q*4];
          const f32x4 sh4 = *(const f32x4*)&affine[256+128+tc*16+q*4];
          Xs[colbase + tc*8+q*2]   = packh(fmaxf(fmaf(acc2[tc][0],sc4[0],sh4[0]),0.f),
                                           fmaxf(fmaf(acc2[tc][1],sc4[1],sh4[1]),0.f));
          Xs[colbase + tc*8+q*2+1] = packh(fmaxf(fmaf(acc2[tc][2],sc4[2],sh4[2]),0.f),
                                           fmaxf(fmaf(acc2[tc][3],sc4[3],sh4[3]),0.f));
        }
        // ---- layer 3 (128 ch) ----
        f32x4 acc3[8];
        #pragma unroll
        for (int tc=0;tc<8;tc++) acc3[tc]=zero4();
        #pragma unroll
        for (int kc=0;kc<2;kc++){
          f16x8 Bf = *(const f16x8*)&Xs[colbase + kc*16 + q*4];
          #pragma unroll
          for (int tc=0;tc<8;tc++){
            f16x8 Af = *(const f16x8*)&Wf3[((tc*2+kc)*64+lane)*4];
            acc3[tc] = MFMA16(Af,Bf,acc3[tc]);
          }
        }
        u32* mmb = &mm[(ch&1)*512];
        #pragma unroll
        for (int tc=0;tc<8;tc++){
          #pragma unroll
          for (int r=0;r<4;r++){
            float y=acc3[tc][r];
            float s1=y, s2=__fmul_rn(y,y);
            u32 pm = packh(y, -y);                       // (max, -min) carrier
            #pragma unroll
            for (int off=1;off<16;off<<=1){
              s1+=__shfl_xor(s1,off); s2+=__shfl_xor(s2,off);
              u32 o = (u32)__shfl_xor((int)pm,off);
              pm = asU32(__builtin_elementwise_max(asH2(pm), asH2(o)));
            }
            if (n==0){ const int c=tc*16+q*4+r;
              atomicAdd(&bins[c], s1); atomicAdd(&bins[128+c], s2);
              mmb[w*128+c]=pm; }
          }
        }
        __syncthreads();                                 // mm panel ready
        {
          const int c = t&127, gg = t>>7;                // 2 centers per chunk
          u32 a = mmb[(2*gg)*128+c], b2 = mmb[(2*gg+1)*128+c];
          h2v hm = __builtin_elementwise_max(asH2(a), asH2(b2));
          const int s0 = inner*8 + ch*2 + gg;
          outMM[((size_t)bb*128+c)*NS + s0] = packh((float)hm[0], -(float)hm[1]);
        }
      }
    }
  }

  __syncthreads();
  if (t < TCO){
    atomicAdd(&stats[STAGE*256 + 2*t],   bins[t]);
    atomicAdd(&stats[STAGE*256 + 2*t+1], bins[TCO+t]);
  }
}

// ----------------------------------------------------------- finalize ----
// affine SoA per layer: af[c]=scale, af[128+c]=shift
__global__ void finalize_kernel(const float* __restrict__ st, float* __restrict__ af,
                                const float* __restrict__ gamma, const float* __restrict__ beta, int C)
{
  int c = threadIdx.x;
  if (c < C){
    float mean = st[2*c] * (1.f/524288.f);
    float var  = fmaxf(st[2*c+1] * (1.f/524288.f) - mean*mean, 0.f);
    float rstd = 1.f / sqrtf(var + 1e-5f);
    float sc = rstd * gamma[c];
    af[c]     = sc;
    af[128+c] = beta[c] - mean*sc;
  }
}

// -------------------------------------------------------------- apply ----
__global__ void apply_kernel(const float* __restrict__ affine, float* __restrict__ outF)
{
  const int i = blockIdx.x*256 + threadIdx.x;      // 16*128*1024 elements
  const int c = (i >> 10) & 127;
  u32 v = ((const u32*)outF)[i];
  h2v h = asH2(v);
  float sc = affine[512+c], sh = affine[512+128+c];
  float cand = (sc > 0.f) ? (float)h[0] : (float)h[1];
  outF[i] = fmaxf(fmaf(cand, sc, sh), 0.f);
}

// ------------------------------------------------------------- launch ----
extern "C" void kernel_launch(void* const* d_in, const int* in_sizes, int n_in,
                              void* d_out, int out_size, void* d_ws, size_t ws_size,
                              hipStream_t stream)
{
  (void)in_sizes; (void)n_in; (void)out_size; (void)ws_size;
  const float* xyz  = (const float*)d_in[0];
  const float* feat = (const float*)d_in[1];
  const float* W0 = (const float*)d_in[2];
  const float* g0 = (const float*)d_in[3];
  const float* b0 = (const float*)d_in[4];
  const float* W1 = (const float*)d_in[5];
  const float* g1 = (const float*)d_in[6];
  const float* b1 = (const float*)d_in[7];
  const float* W2 = (const float*)d_in[8];
  const float* g2 = (const float*)d_in[9];
  const float* b2 = (const float*)d_in[10];

  char* ws = (char*)d_ws;                      // 1,087,488 B total (< proven 1,088,512)
  u16*   gidx    = (u16*)  (ws + 0);           // 524288 u16  = 1048576 B
  u32*   Wf1     = (u32*)  (ws + 1048576);     // 2048 u32    =    8192 B
  u32*   Wf2     = (u32*)  (ws + 1056768);     // 2048 u32    =    8192 B
  u32*   Wf3     = (u32*)  (ws + 1064960);     // 4096 u32    =   16384 B
  float* stats   = (float*)(ws + 1081344);     // 768 f32     =    3072 B
  float* affine  = (float*)(ws + 1084416);     // 768 f32     =    3072 B

  float* out_xyz  = (float*)d_out;                         // (16,3,1024) f32
  float* out_feat = (float*)d_out + (size_t)NB*3*NS;       // (16,128,1024) f32

  prep_kernel<<<1,256,0,stream>>>(W0,W1,W2,Wf1,Wf2,Wf3,stats);
  fps_kernel<<<NB,1024,0,stream>>>(xyz, out_xyz);
  ballq_kernel<<<NB*NS/4,256,0,stream>>>(xyz, out_xyz, gidx);

  mlp_pass<0><<<NSAMP/256,256,0,stream>>>(xyz,feat,out_xyz,gidx,Wf1,Wf2,Wf3,W0,affine,stats,(u32*)out_feat);
  finalize_kernel<<<1,128,0,stream>>>(stats,     affine,     g0,b0, 64);
  mlp_pass<1><<<NSAMP/256,256,0,stream>>>(xyz,feat,out_xyz,gidx,Wf1,Wf2,Wf3,W0,affine,stats,(u32*)out_feat);
  finalize_kernel<<<1,128,0,stream>>>(stats+256, affine+256, g1,b1, 64);
  mlp_pass<2><<<NSAMP/256,256,0,stream>>>(xyz,feat,out_xyz,gidx,Wf1,Wf2,Wf3,W0,affine,stats,(u32*)out_feat);
  finalize_kernel<<<1,128,0,stream>>>(stats+512, affine+512, g2,b2, 128);
  apply_kernel<<<(NB*128*NS)/256,256,0,stream>>>(affine, out_feat);
}

// Round 12
// 2011.339 us; speedup vs baseline: 1.0084x; 1.0084x over previous
//
#include <hip/hip_runtime.h>

// PointNetSAModule on MI355X (gfx950).
// B=16, N=8192, CIN=64, S=1024, K=32, radius=0.2, MLP 67->64->64->128, eps=1e-5.
// Inputs/outputs float32 (proven R4). ws footprint = 1,087,488 B (< proven 1,088,512).
//
// R11 -> R12:
//  * fps: back to R10's single-barrier u64-key DPP skeleton (R11's 2-barrier
//    value+match scheme regressed: VALU -14% but +20% idle). d^2 now computed
//    in PACKED f32 pairs (v_pk_add/mul_f32, contract(off) keeps IEEE-exact
//    separate mul/add) -> update loop ~halved.
//  * mlp: launch_bounds (256,2)->(256,4): 12.8KB LDS, VGPR 52 -> 4 blocks/CU.

typedef unsigned short u16;
typedef unsigned int   u32;
typedef unsigned long long u64;

#define NB    16
#define NPTS  8192
#define CINF  64
#define NS    1024
#define KK    32
#define NSAMP (NB*NS*KK)   // 524288

typedef _Float16 h2v   __attribute__((ext_vector_type(2)));
typedef _Float16 f16x8 __attribute__((ext_vector_type(8)));
typedef float    f32x4 __attribute__((ext_vector_type(4)));
typedef float    f32x2 __attribute__((ext_vector_type(2)));

static __device__ __forceinline__ h2v asH2(u32 x){ union{u32 u; h2v h;} v; v.u=x; return v.h; }
static __device__ __forceinline__ u32 asU32(h2v h){ union{u32 u; h2v h;} v; v.h=h; return v.u; }
static __device__ __forceinline__ u32 packh(float lo, float hi){
  union{ _Float16 h[2]; u32 u; } v;
  v.h[0]=(_Float16)lo; v.h[1]=(_Float16)hi; return v.u;
}
static __device__ __forceinline__ f32x4 zero4(){ f32x4 z; z[0]=0.f;z[1]=0.f;z[2]=0.f;z[3]=0.f; return z; }
static __device__ __forceinline__ f16x8 zero8h(){
  f16x8 z;
  #pragma unroll
  for (int i=0;i<8;i++) z[i]=(_Float16)0.f;
  return z;
}

// exact-order d^2, matching numpy f32: (dx*dx + dy*dy) + dz*dz, no FMA contraction
static __device__ __forceinline__ float d2_exact(float ax,float ay,float az,float bx,float by,float bz){
  float dx=__fsub_rn(ax,bx), dy=__fsub_rn(ay,by), dz=__fsub_rn(az,bz);
  return __fadd_rn(__fadd_rn(__fmul_rn(dx,dx),__fmul_rn(dy,dy)),__fmul_rn(dz,dz));
}

// one DPP combine level for the (kv,ki) lexicographic max (VALU pipe)
template<int CTRL, int RMASK>
static __device__ __forceinline__ void dppmax(u32 &kv, u32 &ki){
  u32 okv = (u32)__builtin_amdgcn_update_dpp((int)kv, (int)kv, CTRL, RMASK, 0xf, false);
  u32 oki = (u32)__builtin_amdgcn_update_dpp((int)ki, (int)ki, CTRL, RMASK, 0xf, false);
  u64 A = (((u64)okv)<<32) | oki;
  u64 B = (((u64)kv )<<32) | ki;
  if (A > B){ kv = okv; ki = oki; }
}

// ---------------------------------------------------------------- prep ----
// A-operand fragments in exact MFMA lane order: entry ((tc*2+kc)*64+lane)*4+d,
// lane m=lane&15 (channel row), q=lane>>4, k=kc*32+q*8+{2d,2d+1}.
__global__ void prep_kernel(const float* __restrict__ W0, const float* __restrict__ W1,
                            const float* __restrict__ W2,
                            u32* __restrict__ Wf1, u32* __restrict__ Wf2, u32* __restrict__ Wf3,
                            float* __restrict__ stats)
{
  const int t = threadIdx.x;
  for (int i=t;i<768;i+=256) stats[i]=0.f;
  for (int i=t;i<2048;i+=256){           // L1: 4 tiles x 2 chunks (feat cols only)
    int d=i&3, lane=(i>>2)&63, kc=(i>>8)&1, tc=i>>9;
    int row=tc*16+(lane&15), k0=kc*32+(lane>>4)*8+2*d;
    Wf1[i]=packh(W0[row*67+3+k0], W0[row*67+4+k0]);
  }
  for (int i=t;i<2048;i+=256){           // L2
    int d=i&3, lane=(i>>2)&63, kc=(i>>8)&1, tc=i>>9;
    int row=tc*16+(lane&15), k0=kc*32+(lane>>4)*8+2*d;
    Wf2[i]=packh(W1[row*64+k0], W1[row*64+k0+1]);
  }
  for (int i=t;i<4096;i+=256){           // L3
    int d=i&3, lane=(i>>2)&63, kc=(i>>8)&1, tc=i>>9;
    int row=tc*16+(lane&15), k0=kc*32+(lane>>4)*8+2*d;
    Wf3[i]=packh(W2[row*64+k0], W2[row*64+k0+1]);
  }
}

// ----------------------------------------------------------------- FPS ----
// one block per batch; 1024 threads, 8 consecutive points/thread in LDS
// (28-f32 regions, 2-way banks = free). dist kept as 4x f32x2 in regs.
// d^2 in packed-f32 pairs (contract(off) -> exact IEEE mul/add like numpy).
// Argmax: u64 key (dist_bits<<32 | 8191-idx), 6 DPP levels -> lane63 ->
// 16 LDS slots -> 4 DPP levels -> scalar winner. Single barrier per step.
__global__ __launch_bounds__(1024,1) void fps_kernel(const float* __restrict__ xyz,
    float* __restrict__ out_xyz)
{
  __shared__ float sc[1024*28];            // 114,688 B
  __shared__ u32 s_kv[2][16], s_ki[2][16];
  const int b = blockIdx.x, t = threadIdx.x;
  const float* xb = xyz + (size_t)b*3*NPTS;
  const int tb = t*28;
  #pragma unroll
  for (int i=0;i<8;i++){
    const int idx = 8*t + i;
    sc[tb+i]    = xb[idx];
    sc[tb+8+i]  = xb[NPTS+idx];
    sc[tb+16+i] = xb[2*NPTS+idx];
  }
  f32x2 d[4];
  #pragma unroll
  for (int i=0;i<4;i++){ d[i][0]=__builtin_inff(); d[i][1]=__builtin_inff(); }
  __syncthreads();
  float cx = xb[0], cy = xb[NPTS], cz = xb[2*NPTS];   // initial center = point 0
  const int lane = t & 63, wv = t >> 6, l16 = lane & 15;
  const u32 kibase = (u32)(NPTS-1 - 8*t);
  for (int step=0; step<NS; step++){
    if (t==0){
      out_xyz[(size_t)(b*3+0)*NS+step]=cx;
      out_xyz[(size_t)(b*3+1)*NS+step]=cy;
      out_xyz[(size_t)(b*3+2)*NS+step]=cz;
    }
    if (step==NS-1) break;
    f32x4 X0 = *(const f32x4*)&sc[tb];
    f32x4 X1 = *(const f32x4*)&sc[tb+4];
    f32x4 Y0 = *(const f32x4*)&sc[tb+8];
    f32x4 Y1 = *(const f32x4*)&sc[tb+12];
    f32x4 Z0 = *(const f32x4*)&sc[tb+16];
    f32x4 Z1 = *(const f32x4*)&sc[tb+20];
    u32 bkv = 0, bki = 0xffffffffu;        // sentinel: loses to every real key
    {
      #pragma clang fp contract(off)       // keep IEEE separate mul/add (numpy order)
      f32x2 cpx; cpx[0]=cx; cpx[1]=cx;
      f32x2 cpy; cpy[0]=cy; cpy[1]=cy;
      f32x2 cpz; cpz[0]=cz; cpz[1]=cz;
#define UPDP(pi, PX, PY, PZ) { \
      f32x2 dx = (PX) - cpx, dy = (PY) - cpy, dz = (PZ) - cpz; \
      f32x2 t1 = dx*dx; f32x2 t2 = dy*dy; f32x2 t3 = t1 + t2; \
      f32x2 t4 = dz*dz; f32x2 dd = t3 + t4; \
      f32x2 nd = __builtin_elementwise_min(dd, d[pi]); d[pi]=nd; \
      { u32 kv = __float_as_uint(nd[0]), ki = kibase - 2*(pi); \
        u64 A=(((u64)kv)<<32)|ki, Bq=(((u64)bkv)<<32)|bki; \
        if (A > Bq){ bkv=kv; bki=ki; } } \
      { u32 kv = __float_as_uint(nd[1]), ki = kibase - (2*(pi)+1); \
        u64 A=(((u64)kv)<<32)|ki, Bq=(((u64)bkv)<<32)|bki; \
        if (A > Bq){ bkv=kv; bki=ki; } } }
      UPDP(0, X0.lo, Y0.lo, Z0.lo)
      UPDP(1, X0.hi, Y0.hi, Z0.hi)
      UPDP(2, X1.lo, Y1.lo, Z1.lo)
      UPDP(3, X1.hi, Y1.hi, Z1.hi)
#undef UPDP
    }
    dppmax<0xB1,0xf>(bkv,bki);           // quad_perm xor1
    dppmax<0x4E,0xf>(bkv,bki);           // quad_perm xor2
    dppmax<0x141,0xf>(bkv,bki);          // row_half_mirror
    dppmax<0x140,0xf>(bkv,bki);          // row_mirror
    dppmax<0x142,0xa>(bkv,bki);          // row_bcast15 (rows 1,3)
    dppmax<0x143,0xc>(bkv,bki);          // row_bcast31 (rows 2,3) -> lane 63
    const u32 wkv = (u32)__builtin_amdgcn_readlane((int)bkv, 63);
    const u32 wki = (u32)__builtin_amdgcn_readlane((int)bki, 63);
    const int p = step&1;                // double-buffered -> single barrier/step
    if (lane==0){ s_kv[p][wv]=wkv; s_ki[p][wv]=wki; }
    __syncthreads();
    u32 kv2 = s_kv[p][l16], ki2 = s_ki[p][l16];
    dppmax<0xB1,0xf>(kv2,ki2);
    dppmax<0x4E,0xf>(kv2,ki2);
    dppmax<0x141,0xf>(kv2,ki2);
    dppmax<0x140,0xf>(kv2,ki2);          // lanes 0..15 hold block winner
    const int widx = (NPTS-1) - (int)__builtin_amdgcn_readfirstlane((int)ki2);
    const int wb2 = (widx>>3)*28, wi = widx&7;
    cx = sc[wb2+wi]; cy = sc[wb2+8+wi]; cz = sc[wb2+16+wi];
  }
}

// ---------------------------------------------------------- ball query ----
__global__ __launch_bounds__(256) void ballq_kernel(const float* __restrict__ xyz,
    const float* __restrict__ out_xyz, u16* __restrict__ gidx)
{
  const int gid = blockIdx.x*4 + (threadIdx.x>>6);
  const int lane = threadIdx.x & 63;
  const int b = gid >> 10, s = gid & (NS-1);
  const float* xb = xyz + (size_t)b*3*NPTS;
  const float cx = out_xyz[(size_t)(b*3+0)*NS+s];
  const float cy = out_xyz[(size_t)(b*3+1)*NS+s];
  const float cz = out_xyz[(size_t)(b*3+2)*NS+s];
  u16* out = gidx + (size_t)gid*KK;
  int cnt=0, first=-1;
  for (int base=0; base<NPTS; base+=64){
    const int pidx = base + lane;
    float d2 = d2_exact(cx,cy,cz, xb[pidx], xb[NPTS+pidx], xb[2*NPTS+pidx]);
    bool within = d2 < 0.04f;
    unsigned long long m = __ballot(within);
    if (m){
      if (first<0) first = base + (__ffsll(m)-1);
      int pos = cnt + (int)__popcll(m & ((1ull<<lane)-1ull));
      if (within && pos<KK) out[pos]=(u16)pidx;
      cnt += (int)__popcll(m);
      if (cnt>=KK) break;
    }
  }
  if (first<0) first=0;
  for (int posi = cnt + lane; posi < KK; posi += 64) out[posi]=(u16)first;
}

// --------------------------------------------------------------- MLP -----
// STAGE 0: stats(y1) | 1: stats(y2) | 2: stats(y3) + (max,min) over K -> out.
// Block = 256 thr = 4 waves; 4 chunks x 64 samples; wave owns 16 samples.
// XCD-affinity swizzle: slot=blk&7 -> batches {2slot, 2slot+1} (4MB feat = L2).
#define MFMA16(A,B,C) __builtin_amdgcn_mfma_f32_16x16x32_f16(A,B,C,0,0,0)

template<int STAGE>
__global__ __launch_bounds__(256,4) void mlp_pass(
    const float* __restrict__ xyz, const float* __restrict__ feat,
    const float* __restrict__ out_xyz, const u16* __restrict__ gidx,
    const u32* __restrict__ Wf1, const u32* __restrict__ Wf2, const u32* __restrict__ Wf3,
    const float* __restrict__ W0raw,
    const float* __restrict__ affine, float* __restrict__ stats, u32* __restrict__ outMM)
{
  constexpr int TCO = (STAGE==2)?128:64;
  __shared__ alignas(16) u32 Xs[64*48];          // 12 KB
  __shared__ float bins[2*TCO];
  __shared__ u32 mm[(STAGE==2)? 2*4*128 : 4];    // double-buffered cross-wave panel

  const int t = threadIdx.x;
  const int lane = t&63, w = t>>6, n = lane&15, q = lane>>4;
  const int j = t>>2, q4 = t&3;                  // gather role: sample j, quarter q4
  const int colbase = (w*16+n)*48;
  // XCD-affinity block swizzle (bijective on [0,2048))
  const int u_   = blockIdx.x;
  const int slot = u_ & 7, rr = u_ >> 3;
  const int bb   = slot*2 + (rr>>7);
  const int inner= rr & 127;
  if (t < 2*TCO) bins[t]=0.f;
  __syncthreads();                               // bins zero visible to all

  #pragma unroll 1
  for (int ch=0; ch<4; ch++){
    const int ss = (bb*128 + inner)*256 + ch*64 + j;   // flat (b,s,k)
    const int b = ss >> 15;
    const int s = (ss >> 5) & (NS-1);
    const int g = ((int)gidx[ss]) & (NPTS-1);
    // ---- gather: 4 threads per sample, 16 feats each; q4==3 adds dxyz ----
    {
      const float* fb = feat + (size_t)b*CINF*NPTS + g;
      u32* Xrow = &Xs[j*48];
      #pragma unroll
      for (int m2=0;m2<8;m2++){
        float a0 = fb[(size_t)(16*q4+2*m2)*NPTS];
        float a1 = fb[(size_t)(16*q4+2*m2+1)*NPTS];
        Xrow[8*q4+m2] = packh(a0,a1);
      }
      if (q4==3){
        const float* xb = xyz + (size_t)b*3*NPTS;
        float dx=__fsub_rn(xb[g],        out_xyz[(size_t)(b*3+0)*NS+s]);
        float dy=__fsub_rn(xb[NPTS+g],   out_xyz[(size_t)(b*3+1)*NS+s]);
        float dz=__fsub_rn(xb[2*NPTS+g], out_xyz[(size_t)(b*3+2)*NS+s]);
        Xrow[32]=packh(dx,dy); Xrow[33]=packh(dz,0.f);
      }
      #pragma unroll
      for (int i=34+q4;i<48;i+=4) Xrow[i]=0;
    }
    // ---- layer 1: Y1(64ch x 16smp) = W0 * X ----
    f32x4 acc[4];
    #pragma unroll
    for (int tc=0;tc<4;tc++) acc[tc]=zero4();
    #pragma unroll
    for (int kc=0;kc<2;kc++){
      f16x8 Bf = *(const f16x8*)&Xs[colbase + kc*16 + q*4];
      #pragma unroll
      for (int tc=0;tc<4;tc++){
        f16x8 Af = *(const f16x8*)&Wf1[((tc*2+kc)*64+lane)*4];
        acc[tc] = MFMA16(Af,Bf,acc[tc]);
      }
    }
    {  // xyz chunk: only q==0 of A nonzero (W0 cols 0..2), B dwords 32..47
      f16x8 Bf = *(const f16x8*)&Xs[colbase + 32 + q*4];
      #pragma unroll
      for (int tc=0;tc<4;tc++){
        f16x8 Af = zero8h();
        if (q==0){
          const int row = tc*16+n;
          Af[0]=(_Float16)W0raw[row*67+0];
          Af[1]=(_Float16)W0raw[row*67+1];
          Af[2]=(_Float16)W0raw[row*67+2];
        }
        acc[tc] = MFMA16(Af,Bf,acc[tc]);
      }
    }

    if constexpr (STAGE==0){
      #pragma unroll
      for (int tc=0;tc<4;tc++){
        #pragma unroll
        for (int r=0;r<4;r++){
          float s1=acc[tc][r], s2=__fmul_rn(s1,s1);
          #pragma unroll
          for (int off=1;off<16;off<<=1){ s1+=__shfl_xor(s1,off); s2+=__shfl_xor(s2,off); }
          if (n==0){ const int c=tc*16+q*4+r;
            atomicAdd(&bins[c], s1); atomicAdd(&bins[TCO+c], s2); }
        }
      }
    } else {
      // affine L1 + relu -> f16 -> X panel
      #pragma unroll
      for (int tc=0;tc<4;tc++){
        const f32x4 sc4 = *(const f32x4*)&affine[tc*16+q*4];
        const f32x4 sh4 = *(const f32x4*)&affine[128+tc*16+q*4];
        Xs[colbase + tc*8+q*2]   = packh(fmaxf(fmaf(acc[tc][0],sc4[0],sh4[0]),0.f),
                                         fmaxf(fmaf(acc[tc][1],sc4[1],sh4[1]),0.f));
        Xs[colbase + tc*8+q*2+1] = packh(fmaxf(fmaf(acc[tc][2],sc4[2],sh4[2]),0.f),
                                         fmaxf(fmaf(acc[tc][3],sc4[3],sh4[3]),0.f));
      }
      // ---- layer 2 ----
      f32x4 acc2[4];
      #pragma unroll
      for (int tc=0;tc<4;tc++) acc2[tc]=zero4();
      #pragma unroll
      for (int kc=0;kc<2;kc++){
        f16x8 Bf = *(const f16x8*)&Xs[colbase + kc*16 + q*4];
        #pragma unroll
        for (int tc=0;tc<4;tc++){
          f16x8 Af = *(const f16x8*)&Wf2[((tc*2+kc)*64+lane)*4];
          acc2[tc] = MFMA16(Af,Bf,acc2[tc]);
        }
      }
      if constexpr (STAGE==1){
        #pragma unroll
        for (int tc=0;tc<4;tc++){
          #pragma unroll
          for (int r=0;r<4;r++){
            float s1=acc2[tc][r], s2=__fmul_rn(s1,s1);
            #pragma unroll
            for (int off=1;off<16;off<<=1){ s1+=__shfl_xor(s1,off); s2+=__shfl_xor(s2,off); }
            if (n==0){ const int c=tc*16+q*4+r;
              atomicAdd(&bins[c], s1); atomicAdd(&bins[TCO+c], s2); }
          }
        }
      } else {
        #pragma unroll
        for (int tc=0;tc<4;tc++){
          const f32x4 sc4 = *(const f32x4*)&affine[256+tc*16+q*4];
          const f32x4 sh4 = *(const f32x4*)&affine[256+128+tc*16+q*4];
          Xs[colbase + tc*8+q*2]   = packh(fmaxf(fmaf(acc2[tc][0],sc4[0],sh4[0]),0.f),
                                           fmaxf(fmaf(acc2[tc][1],sc4[1],sh4[1]),0.f));
          Xs[colbase + tc*8+q*2+1] = packh(fmaxf(fmaf(acc2[tc][2],sc4[2],sh4[2]),0.f),
                                           fmaxf(fmaf(acc2[tc][3],sc4[3],sh4[3]),0.f));
        }
        // ---- layer 3 (128 ch) ----
        f32x4 acc3[8];
        #pragma unroll
        for (int tc=0;tc<8;tc++) acc3[tc]=zero4();
        #pragma unroll
        for (int kc=0;kc<2;kc++){
          f16x8 Bf = *(const f16x8*)&Xs[colbase + kc*16 + q*4];
          #pragma unroll
          for (int tc=0;tc<8;tc++){
            f16x8 Af = *(const f16x8*)&Wf3[((tc*2+kc)*64+lane)*4];
            acc3[tc] = MFMA16(Af,Bf,acc3[tc]);
          }
        }
        u32* mmb = &mm[(ch&1)*512];
        #pragma unroll
        for (int tc=0;tc<8;tc++){
          #pragma unroll
          for (int r=0;r<4;r++){
            float y=acc3[tc][r];
            float s1=y, s2=__fmul_rn(y,y);
            u32 pm = packh(y, -y);                       // (max, -min) carrier
            #pragma unroll
            for (int off=1;off<16;off<<=1){
              s1+=__shfl_xor(s1,off); s2+=__shfl_xor(s2,off);
              u32 o = (u32)__shfl_xor((int)pm,off);
              pm = asU32(__builtin_elementwise_max(asH2(pm), asH2(o)));
            }
            if (n==0){ const int c=tc*16+q*4+r;
              atomicAdd(&bins[c], s1); atomicAdd(&bins[128+c], s2);
              mmb[w*128+c]=pm; }
          }
        }
        __syncthreads();                                 // mm panel ready
        {
          const int c = t&127, gg = t>>7;                // 2 centers per chunk
          u32 a = mmb[(2*gg)*128+c], b2 = mmb[(2*gg+1)*128+c];
          h2v hm = __builtin_elementwise_max(asH2(a), asH2(b2));
          const int s0 = inner*8 + ch*2 + gg;
          outMM[((size_t)bb*128+c)*NS + s0] = packh((float)hm[0], -(float)hm[1]);
        }
      }
    }
  }

  __syncthreads();
  if (t < TCO){
    atomicAdd(&stats[STAGE*256 + 2*t],   bins[t]);
    atomicAdd(&stats[STAGE*256 + 2*t+1], bins[TCO+t]);
  }
}

// ----------------------------------------------------------- finalize ----
// affine SoA per layer: af[c]=scale, af[128+c]=shift
__global__ void finalize_kernel(const float* __restrict__ st, float* __restrict__ af,
                                const float* __restrict__ gamma, const float* __restrict__ beta, int C)
{
  int c = threadIdx.x;
  if (c < C){
    float mean = st[2*c] * (1.f/524288.f);
    float var  = fmaxf(st[2*c+1] * (1.f/524288.f) - mean*mean, 0.f);
    float rstd = 1.f / sqrtf(var + 1e-5f);
    float sc = rstd * gamma[c];
    af[c]     = sc;
    af[128+c] = beta[c] - mean*sc;
  }
}

// -------------------------------------------------------------- apply ----
__global__ void apply_kernel(const float* __restrict__ affine, float* __restrict__ outF)
{
  const int i = blockIdx.x*256 + threadIdx.x;      // 16*128*1024 elements
  const int c = (i >> 10) & 127;
  u32 v = ((const u32*)outF)[i];
  h2v h = asH2(v);
  float sc = affine[512+c], sh = affine[512+128+c];
  float cand = (sc > 0.f) ? (float)h[0] : (float)h[1];
  outF[i] = fmaxf(fmaf(cand, sc, sh), 0.f);
}

// ------------------------------------------------------------- launch ----
extern "C" void kernel_launch(void* const* d_in, const int* in_sizes, int n_in,
                              void* d_out, int out_size, void* d_ws, size_t ws_size,
                              hipStream_t stream)
{
  (void)in_sizes; (void)n_in; (void)out_size; (void)ws_size;
  const float* xyz  = (const float*)d_in[0];
  const float* feat = (const float*)d_in[1];
  const float* W0 = (const float*)d_in[2];
  const float* g0 = (const float*)d_in[3];
  const float* b0 = (const float*)d_in[4];
  const float* W1 = (const float*)d_in[5];
  const float* g1 = (const float*)d_in[6];
  const float* b1 = (const float*)d_in[7];
  const float* W2 = (const float*)d_in[8];
  const float* g2 = (const float*)d_in[9];
  const float* b2 = (const float*)d_in[10];

  char* ws = (char*)d_ws;                      // 1,087,488 B total (< proven 1,088,512)
  u16*   gidx    = (u16*)  (ws + 0);           // 524288 u16  = 1048576 B
  u32*   Wf1     = (u32*)  (ws + 1048576);     // 2048 u32    =    8192 B
  u32*   Wf2     = (u32*)  (ws + 1056768);     // 2048 u32    =    8192 B
  u32*   Wf3     = (u32*)  (ws + 1064960);     // 4096 u32    =   16384 B
  float* stats   = (float*)(ws + 1081344);     // 768 f32     =    3072 B
  float* affine  = (float*)(ws + 1084416);     // 768 f32     =    3072 B

  float* out_xyz  = (float*)d_out;                         // (16,3,1024) f32
  float* out_feat = (float*)d_out + (size_t)NB*3*NS;       // (16,128,1024) f32

  prep_kernel<<<1,256,0,stream>>>(W0,W1,W2,Wf1,Wf2,Wf3,stats);
  fps_kernel<<<NB,1024,0,stream>>>(xyz, out_xyz);
  ballq_kernel<<<NB*NS/4,256,0,stream>>>(xyz, out_xyz, gidx);

  mlp_pass<0><<<NSAMP/256,256,0,stream>>>(xyz,feat,out_xyz,gidx,Wf1,Wf2,Wf3,W0,affine,stats,(u32*)out_feat);
  finalize_kernel<<<1,128,0,stream>>>(stats,     affine,     g0,b0, 64);
  mlp_pass<1><<<NSAMP/256,256,0,stream>>>(xyz,feat,out_xyz,gidx,Wf1,Wf2,Wf3,W0,affine,stats,(u32*)out_feat);
  finalize_kernel<<<1,128,0,stream>>>(stats+256, affine+256, g1,b1, 64);
  mlp_pass<2><<<NSAMP/256,256,0,stream>>>(xyz,feat,out_xyz,gidx,Wf1,Wf2,Wf3,W0,affine,stats,(u32*)out_feat);
  finalize_kernel<<<1,128,0,stream>>>(stats+512, affine+512, g2,b2, 128);
  apply_kernel<<<(NB*128*NS)/256,256,0,stream>>>(affine, out_feat);
}

// Round 13
// 1849.620 us; speedup vs baseline: 1.0965x; 1.0874x over previous
//
#include <hip/hip_runtime.h>

// PointNetSAModule on MI355X (gfx950).
// B=16, N=8192, CIN=64, S=1024, K=32, radius=0.2, MLP 67->64->64->128, eps=1e-5.
// Inputs/outputs float32 (proven R4). ws footprint = 1,087,488 B (< proven 1,088,512).
//
// R12 -> R13:
//  * fps: single-barrier skeleton kept; wave stage is VALUE-only DPP fmax
//    (per-point u64 key tracking removed -- R12 counters showed ~290 instr/step
//    vs ~130 modeled; the u64 pair-assembly per point is the gap). Index
//    recovered in-wave: cmp-vs-SGPR + ballot + readlane (lane order == index
//    order). u64 lexicographic keys only in the 16-slot cross-wave stage.
//  * mlp: launch_bounds back to (256,2) -- (256,4) regressed rest 766->865 us.

typedef unsigned short u16;
typedef unsigned int   u32;
typedef unsigned long long u64;

#define NB    16
#define NPTS  8192
#define CINF  64
#define NS    1024
#define KK    32
#define NSAMP (NB*NS*KK)   // 524288

typedef _Float16 h2v   __attribute__((ext_vector_type(2)));
typedef _Float16 f16x8 __attribute__((ext_vector_type(8)));
typedef float    f32x4 __attribute__((ext_vector_type(4)));
typedef float    f32x2 __attribute__((ext_vector_type(2)));

static __device__ __forceinline__ h2v asH2(u32 x){ union{u32 u; h2v h;} v; v.u=x; return v.h; }
static __device__ __forceinline__ u32 asU32(h2v h){ union{u32 u; h2v h;} v; v.h=h; return v.u; }
static __device__ __forceinline__ u32 packh(float lo, float hi){
  union{ _Float16 h[2]; u32 u; } v;
  v.h[0]=(_Float16)lo; v.h[1]=(_Float16)hi; return v.u;
}
static __device__ __forceinline__ f32x4 zero4(){ f32x4 z; z[0]=0.f;z[1]=0.f;z[2]=0.f;z[3]=0.f; return z; }
static __device__ __forceinline__ f16x8 zero8h(){
  f16x8 z;
  #pragma unroll
  for (int i=0;i<8;i++) z[i]=(_Float16)0.f;
  return z;
}

// exact-order d^2, matching numpy f32: (dx*dx + dy*dy) + dz*dz, no FMA contraction
static __device__ __forceinline__ float d2_exact(float ax,float ay,float az,float bx,float by,float bz){
  float dx=__fsub_rn(ax,bx), dy=__fsub_rn(ay,by), dz=__fsub_rn(az,bz);
  return __fadd_rn(__fadd_rn(__fmul_rn(dx,dx),__fmul_rn(dy,dy)),__fmul_rn(dz,dz));
}

// one DPP fmax level (VALU pipe)
template<int CTRL, int RMASK>
static __device__ __forceinline__ float dppfmax(float v){
  int o = __builtin_amdgcn_update_dpp(__float_as_int(v), __float_as_int(v),
                                      CTRL, RMASK, 0xf, false);
  return fmaxf(v, __int_as_float(o));
}

// one DPP combine level for the (kv,ki) lexicographic max (cross-wave stage only)
template<int CTRL, int RMASK>
static __device__ __forceinline__ void dppmax(u32 &kv, u32 &ki){
  u32 okv = (u32)__builtin_amdgcn_update_dpp((int)kv, (int)kv, CTRL, RMASK, 0xf, false);
  u32 oki = (u32)__builtin_amdgcn_update_dpp((int)ki, (int)ki, CTRL, RMASK, 0xf, false);
  u64 A = (((u64)okv)<<32) | oki;
  u64 B = (((u64)kv )<<32) | ki;
  if (A > B){ kv = okv; ki = oki; }
}

// ---------------------------------------------------------------- prep ----
// A-operand fragments in exact MFMA lane order: entry ((tc*2+kc)*64+lane)*4+d,
// lane m=lane&15 (channel row), q=lane>>4, k=kc*32+q*8+{2d,2d+1}.
__global__ void prep_kernel(const float* __restrict__ W0, const float* __restrict__ W1,
                            const float* __restrict__ W2,
                            u32* __restrict__ Wf1, u32* __restrict__ Wf2, u32* __restrict__ Wf3,
                            float* __restrict__ stats)
{
  const int t = threadIdx.x;
  for (int i=t;i<768;i+=256) stats[i]=0.f;
  for (int i=t;i<2048;i+=256){           // L1: 4 tiles x 2 chunks (feat cols only)
    int d=i&3, lane=(i>>2)&63, kc=(i>>8)&1, tc=i>>9;
    int row=tc*16+(lane&15), k0=kc*32+(lane>>4)*8+2*d;
    Wf1[i]=packh(W0[row*67+3+k0], W0[row*67+4+k0]);
  }
  for (int i=t;i<2048;i+=256){           // L2
    int d=i&3, lane=(i>>2)&63, kc=(i>>8)&1, tc=i>>9;
    int row=tc*16+(lane&15), k0=kc*32+(lane>>4)*8+2*d;
    Wf2[i]=packh(W1[row*64+k0], W1[row*64+k0+1]);
  }
  for (int i=t;i<4096;i+=256){           // L3
    int d=i&3, lane=(i>>2)&63, kc=(i>>8)&1, tc=i>>9;
    int row=tc*16+(lane&15), k0=kc*32+(lane>>4)*8+2*d;
    Wf3[i]=packh(W2[row*64+k0], W2[row*64+k0+1]);
  }
}

// ----------------------------------------------------------------- FPS ----
// one block per batch; 1024 threads, 8 consecutive points/thread in LDS
// (28-f32 regions, 2-way banks = free). dist kept as 4x f32x2 in regs.
// Per step: packed min-update -> thread pk-max tree -> 6 DPP fmax -> lane63
// -> SGPR wave max -> in-wave index recovery (cmp/ballot/readlane) -> LDS
// slot -> barrier -> 16-slot u64 DPP reduce -> winner coords. One barrier.
__global__ __launch_bounds__(1024,1) void fps_kernel(const float* __restrict__ xyz,
    float* __restrict__ out_xyz)
{
  __shared__ float sc[1024*28];            // 114,688 B
  __shared__ u32 s_kv[2][16], s_ki[2][16];
  const int b = blockIdx.x, t = threadIdx.x;
  const float* xb = xyz + (size_t)b*3*NPTS;
  const int tb = t*28;
  #pragma unroll
  for (int i=0;i<8;i++){
    const int idx = 8*t + i;
    sc[tb+i]    = xb[idx];
    sc[tb+8+i]  = xb[NPTS+idx];
    sc[tb+16+i] = xb[2*NPTS+idx];
  }
  f32x2 d[4];
  #pragma unroll
  for (int i=0;i<4;i++){ d[i][0]=__builtin_inff(); d[i][1]=__builtin_inff(); }
  __syncthreads();
  float cx = xb[0], cy = xb[NPTS], cz = xb[2*NPTS];   // initial center = point 0
  const int lane = t & 63, wv = t >> 6, l16 = lane & 15;
  for (int step=0; step<NS; step++){
    if (t==0){
      out_xyz[(size_t)(b*3+0)*NS+step]=cx;
      out_xyz[(size_t)(b*3+1)*NS+step]=cy;
      out_xyz[(size_t)(b*3+2)*NS+step]=cz;
    }
    if (step==NS-1) break;
    f32x4 X0 = *(const f32x4*)&sc[tb];
    f32x4 X1 = *(const f32x4*)&sc[tb+4];
    f32x4 Y0 = *(const f32x4*)&sc[tb+8];
    f32x4 Y1 = *(const f32x4*)&sc[tb+12];
    f32x4 Z0 = *(const f32x4*)&sc[tb+16];
    f32x4 Z1 = *(const f32x4*)&sc[tb+20];
    {
      #pragma clang fp contract(off)       // keep IEEE separate mul/add (numpy order)
      f32x2 cpx; cpx[0]=cx; cpx[1]=cx;
      f32x2 cpy; cpy[0]=cy; cpy[1]=cy;
      f32x2 cpz; cpz[0]=cz; cpz[1]=cz;
#define UPDP(pi, PX, PY, PZ) { \
      f32x2 dx = (PX) - cpx, dy = (PY) - cpy, dz = (PZ) - cpz; \
      f32x2 t1 = dx*dx; f32x2 t2 = dy*dy; f32x2 t3 = t1 + t2; \
      f32x2 t4 = dz*dz; f32x2 dd = t3 + t4; \
      d[pi] = __builtin_elementwise_min(dd, d[pi]); }
      UPDP(0, X0.lo, Y0.lo, Z0.lo)
      UPDP(1, X0.hi, Y0.hi, Z0.hi)
      UPDP(2, X1.lo, Y1.lo, Z1.lo)
      UPDP(3, X1.hi, Y1.hi, Z1.hi)
#undef UPDP
    }
    // thread-local max (value only)
    f32x2 m0 = __builtin_elementwise_max(d[0], d[1]);
    f32x2 m1 = __builtin_elementwise_max(d[2], d[3]);
    f32x2 m2 = __builtin_elementwise_max(m0, m1);
    float bv = fmaxf(m2[0], m2[1]);
    // wave value reduce on VALU pipe (result valid in lane 63)
    bv = dppfmax<0xB1,0xf>(bv);          // quad_perm xor1
    bv = dppfmax<0x4E,0xf>(bv);          // quad_perm xor2
    bv = dppfmax<0x141,0xf>(bv);         // row_half_mirror
    bv = dppfmax<0x140,0xf>(bv);         // row_mirror
    bv = dppfmax<0x142,0xa>(bv);         // row_bcast15
    bv = dppfmax<0x143,0xc>(bv);         // row_bcast31 -> lane 63
    const float wmax = __int_as_float(__builtin_amdgcn_readlane(__float_as_int(bv), 63));
    // in-wave index recovery: smallest local i matching, then first lane
    int ci = 8;                          // sentinel
    if (d[3][1]==wmax) ci=7;  if (d[3][0]==wmax) ci=6;
    if (d[2][1]==wmax) ci=5;  if (d[2][0]==wmax) ci=4;
    if (d[1][1]==wmax) ci=3;  if (d[1][0]==wmax) ci=2;
    if (d[0][1]==wmax) ci=1;  if (d[0][0]==wmax) ci=0;
    const int lidx = 8*t + ci;
    unsigned long long mask = __ballot(ci<8);   // nonzero: wave max exists in-wave
    const int fl = __ffsll(mask) - 1;           // first lane = smallest index
    const int widx_wave = __builtin_amdgcn_readlane(lidx, fl);
    const int p = step&1;                // double-buffered -> single barrier/step
    if (lane==0){
      s_kv[p][wv] = __float_as_uint(wmax);
      s_ki[p][wv] = (u32)(NPTS-1 - widx_wave);   // bigger = smaller idx
    }
    __syncthreads();
    // cross-wave: 16 slots -> lanes, 4-level u64 lexicographic DPP reduce
    u32 kv2 = s_kv[p][l16], ki2 = s_ki[p][l16];
    dppmax<0xB1,0xf>(kv2,ki2);
    dppmax<0x4E,0xf>(kv2,ki2);
    dppmax<0x141,0xf>(kv2,ki2);
    dppmax<0x140,0xf>(kv2,ki2);          // lanes 0..15 hold block winner
    const int widx = (NPTS-1) - (int)__builtin_amdgcn_readfirstlane((int)ki2);
    const int wb2 = (widx>>3)*28, wi = widx&7;
    cx = sc[wb2+wi]; cy = sc[wb2+8+wi]; cz = sc[wb2+16+wi];
  }
}

// ---------------------------------------------------------- ball query ----
__global__ __launch_bounds__(256) void ballq_kernel(const float* __restrict__ xyz,
    const float* __restrict__ out_xyz, u16* __restrict__ gidx)
{
  const int gid = blockIdx.x*4 + (threadIdx.x>>6);
  const int lane = threadIdx.x & 63;
  const int b = gid >> 10, s = gid & (NS-1);
  const float* xb = xyz + (size_t)b*3*NPTS;
  const float cx = out_xyz[(size_t)(b*3+0)*NS+s];
  const float cy = out_xyz[(size_t)(b*3+1)*NS+s];
  const float cz = out_xyz[(size_t)(b*3+2)*NS+s];
  u16* out = gidx + (size_t)gid*KK;
  int cnt=0, first=-1;
  for (int base=0; base<NPTS; base+=64){
    const int pidx = base + lane;
    float d2 = d2_exact(cx,cy,cz, xb[pidx], xb[NPTS+pidx], xb[2*NPTS+pidx]);
    bool within = d2 < 0.04f;
    unsigned long long m = __ballot(within);
    if (m){
      if (first<0) first = base + (__ffsll(m)-1);
      int pos = cnt + (int)__popcll(m & ((1ull<<lane)-1ull));
      if (within && pos<KK) out[pos]=(u16)pidx;
      cnt += (int)__popcll(m);
      if (cnt>=KK) break;
    }
  }
  if (first<0) first=0;
  for (int posi = cnt + lane; posi < KK; posi += 64) out[posi]=(u16)first;
}

// --------------------------------------------------------------- MLP -----
// STAGE 0: stats(y1) | 1: stats(y2) | 2: stats(y3) + (max,min) over K -> out.
// Block = 256 thr = 4 waves; 4 chunks x 64 samples; wave owns 16 samples.
// XCD-affinity swizzle: slot=blk&7 -> batches {2slot, 2slot+1} (4MB feat = L2).
#define MFMA16(A,B,C) __builtin_amdgcn_mfma_f32_16x16x32_f16(A,B,C,0,0,0)

template<int STAGE>
__global__ __launch_bounds__(256,2) void mlp_pass(
    const float* __restrict__ xyz, const float* __restrict__ feat,
    const float* __restrict__ out_xyz, const u16* __restrict__ gidx,
    const u32* __restrict__ Wf1, const u32* __restrict__ Wf2, const u32* __restrict__ Wf3,
    const float* __restrict__ W0raw,
    const float* __restrict__ affine, float* __restrict__ stats, u32* __restrict__ outMM)
{
  constexpr int TCO = (STAGE==2)?128:64;
  __shared__ alignas(16) u32 Xs[64*48];          // 12 KB
  __shared__ float bins[2*TCO];
  __shared__ u32 mm[(STAGE==2)? 2*4*128 : 4];    // double-buffered cross-wave panel

  const int t = threadIdx.x;
  const int lane = t&63, w = t>>6, n = lane&15, q = lane>>4;
  const int j = t>>2, q4 = t&3;                  // gather role: sample j, quarter q4
  const int colbase = (w*16+n)*48;
  // XCD-affinity block swizzle (bijective on [0,2048))
  const int u_   = blockIdx.x;
  const int slot = u_ & 7, rr = u_ >> 3;
  const int bb   = slot*2 + (rr>>7);
  const int inner= rr & 127;
  if (t < 2*TCO) bins[t]=0.f;
  __syncthreads();                               // bins zero visible to all

  #pragma unroll 1
  for (int ch=0; ch<4; ch++){
    const int ss = (bb*128 + inner)*256 + ch*64 + j;   // flat (b,s,k)
    const int b = ss >> 15;
    const int s = (ss >> 5) & (NS-1);
    const int g = ((int)gidx[ss]) & (NPTS-1);
    // ---- gather: 4 threads per sample, 16 feats each; q4==3 adds dxyz ----
    {
      const float* fb = feat + (size_t)b*CINF*NPTS + g;
      u32* Xrow = &Xs[j*48];
      #pragma unroll
      for (int m2=0;m2<8;m2++){
        float a0 = fb[(size_t)(16*q4+2*m2)*NPTS];
        float a1 = fb[(size_t)(16*q4+2*m2+1)*NPTS];
        Xrow[8*q4+m2] = packh(a0,a1);
      }
      if (q4==3){
        const float* xb = xyz + (size_t)b*3*NPTS;
        float dx=__fsub_rn(xb[g],        out_xyz[(size_t)(b*3+0)*NS+s]);
        float dy=__fsub_rn(xb[NPTS+g],   out_xyz[(size_t)(b*3+1)*NS+s]);
        float dz=__fsub_rn(xb[2*NPTS+g], out_xyz[(size_t)(b*3+2)*NS+s]);
        Xrow[32]=packh(dx,dy); Xrow[33]=packh(dz,0.f);
      }
      #pragma unroll
      for (int i=34+q4;i<48;i+=4) Xrow[i]=0;
    }
    // ---- layer 1: Y1(64ch x 16smp) = W0 * X ----
    f32x4 acc[4];
    #pragma unroll
    for (int tc=0;tc<4;tc++) acc[tc]=zero4();
    #pragma unroll
    for (int kc=0;kc<2;kc++){
      f16x8 Bf = *(const f16x8*)&Xs[colbase + kc*16 + q*4];
      #pragma unroll
      for (int tc=0;tc<4;tc++){
        f16x8 Af = *(const f16x8*)&Wf1[((tc*2+kc)*64+lane)*4];
        acc[tc] = MFMA16(Af,Bf,acc[tc]);
      }
    }
    {  // xyz chunk: only q==0 of A nonzero (W0 cols 0..2), B dwords 32..47
      f16x8 Bf = *(const f16x8*)&Xs[colbase + 32 + q*4];
      #pragma unroll
      for (int tc=0;tc<4;tc++){
        f16x8 Af = zero8h();
        if (q==0){
          const int row = tc*16+n;
          Af[0]=(_Float16)W0raw[row*67+0];
          Af[1]=(_Float16)W0raw[row*67+1];
          Af[2]=(_Float16)W0raw[row*67+2];
        }
        acc[tc] = MFMA16(Af,Bf,acc[tc]);
      }
    }

    if constexpr (STAGE==0){
      #pragma unroll
      for (int tc=0;tc<4;tc++){
        #pragma unroll
        for (int r=0;r<4;r++){
          float s1=acc[tc][r], s2=__fmul_rn(s1,s1);
          #pragma unroll
          for (int off=1;off<16;off<<=1){ s1+=__shfl_xor(s1,off); s2+=__shfl_xor(s2,off); }
          if (n==0){ const int c=tc*16+q*4+r;
            atomicAdd(&bins[c], s1); atomicAdd(&bins[TCO+c], s2); }
        }
      }
    } else {
      // affine L1 + relu -> f16 -> X panel
      #pragma unroll
      for (int tc=0;tc<4;tc++){
        const f32x4 sc4 = *(const f32x4*)&affine[tc*16+q*4];
        const f32x4 sh4 = *(const f32x4*)&affine[128+tc*16+q*4];
        Xs[colbase + tc*8+q*2]   = packh(fmaxf(fmaf(acc[tc][0],sc4[0],sh4[0]),0.f),
                                         fmaxf(fmaf(acc[tc][1],sc4[1],sh4[1]),0.f));
        Xs[colbase + tc*8+q*2+1] = packh(fmaxf(fmaf(acc[tc][2],sc4[2],sh4[2]),0.f),
                                         fmaxf(fmaf(acc[tc][3],sc4[3],sh4[3]),0.f));
      }
      // ---- layer 2 ----
      f32x4 acc2[4];
      #pragma unroll
      for (int tc=0;tc<4;tc++) acc2[tc]=zero4();
      #pragma unroll
      for (int kc=0;kc<2;kc++){
        f16x8 Bf = *(const f16x8*)&Xs[colbase + kc*16 + q*4];
        #pragma unroll
        for (int tc=0;tc<4;tc++){
          f16x8 Af = *(const f16x8*)&Wf2[((tc*2+kc)*64+lane)*4];
          acc2[tc] = MFMA16(Af,Bf,acc2[tc]);
        }
      }
      if constexpr (STAGE==1){
        #pragma unroll
        for (int tc=0;tc<4;tc++){
          #pragma unroll
          for (int r=0;r<4;r++){
            float s1=acc2[tc][r], s2=__fmul_rn(s1,s1);
            #pragma unroll
            for (int off=1;off<16;off<<=1){ s1+=__shfl_xor(s1,off); s2+=__shfl_xor(s2,off); }
            if (n==0){ const int c=tc*16+q*4+r;
              atomicAdd(&bins[c], s1); atomicAdd(&bins[TCO+c], s2); }
          }
        }
      } else {
        #pragma unroll
        for (int tc=0;tc<4;tc++){
          const f32x4 sc4 = *(const f32x4*)&affine[256+tc*16+q*4];
          const f32x4 sh4 = *(const f32x4*)&affine[256+128+tc*16+q*4];
          Xs[colbase + tc*8+q*2]   = packh(fmaxf(fmaf(acc2[tc][0],sc4[0],sh4[0]),0.f),
                                           fmaxf(fmaf(acc2[tc][1],sc4[1],sh4[1]),0.f));
          Xs[colbase + tc*8+q*2+1] = packh(fmaxf(fmaf(acc2[tc][2],sc4[2],sh4[2]),0.f),
                                           fmaxf(fmaf(acc2[tc][3],sc4[3],sh4[3]),0.f));
        }
        // ---- layer 3 (128 ch) ----
        f32x4 acc3[8];
        #pragma unroll
        for (int tc=0;tc<8;tc++) acc3[tc]=zero4();
        #pragma unroll
        for (int kc=0;kc<2;kc++){
          f16x8 Bf = *(const f16x8*)&Xs[colbase + kc*16 + q*4];
          #pragma unroll
          for (int tc=0;tc<8;tc++){
            f16x8 Af = *(const f16x8*)&Wf3[((tc*2+kc)*64+lane)*4];
            acc3[tc] = MFMA16(Af,Bf,acc3[tc]);
          }
        }
        u32* mmb = &mm[(ch&1)*512];
        #pragma unroll
        for (int tc=0;tc<8;tc++){
          #pragma unroll
          for (int r=0;r<4;r++){
            float y=acc3[tc][r];
            float s1=y, s2=__fmul_rn(y,y);
            u32 pm = packh(y, -y);                       // (max, -min) carrier
            #pragma unroll
            for (int off=1;off<16;off<<=1){
              s1+=__shfl_xor(s1,off); s2+=__shfl_xor(s2,off);
              u32 o = (u32)__shfl_xor((int)pm,off);
              pm = asU32(__builtin_elementwise_max(asH2(pm), asH2(o)));
            }
            if (n==0){ const int c=tc*16+q*4+r;
              atomicAdd(&bins[c], s1); atomicAdd(&bins[128+c], s2);
              mmb[w*128+c]=pm; }
          }
        }
        __syncthreads();                                 // mm panel ready
        {
          const int c = t&127, gg = t>>7;                // 2 centers per chunk
          u32 a = mmb[(2*gg)*128+c], b2 = mmb[(2*gg+1)*128+c];
          h2v hm = __builtin_elementwise_max(asH2(a), asH2(b2));
          const int s0 = inner*8 + ch*2 + gg;
          outMM[((size_t)bb*128+c)*NS + s0] = packh((float)hm[0], -(float)hm[1]);
        }
      }
    }
  }

  __syncthreads();
  if (t < TCO){
    atomicAdd(&stats[STAGE*256 + 2*t],   bins[t]);
    atomicAdd(&stats[STAGE*256 + 2*t+1], bins[TCO+t]);
  }
}

// ----------------------------------------------------------- finalize ----
// affine SoA per layer: af[c]=scale, af[128+c]=shift
__global__ void finalize_kernel(const float* __restrict__ st, float* __restrict__ af,
                                const float* __restrict__ gamma, const float* __restrict__ beta, int C)
{
  int c = threadIdx.x;
  if (c < C){
    float mean = st[2*c] * (1.f/524288.f);
    float var  = fmaxf(st[2*c+1] * (1.f/524288.f) - mean*mean, 0.f);
    float rstd = 1.f / sqrtf(var + 1e-5f);
    float sc = rstd * gamma[c];
    af[c]     = sc;
    af[128+c] = beta[c] - mean*sc;
  }
}

// -------------------------------------------------------------- apply ----
__global__ void apply_kernel(const float* __restrict__ affine, float* __restrict__ outF)
{
  const int i = blockIdx.x*256 + threadIdx.x;      // 16*128*1024 elements
  const int c = (i >> 10) & 127;
  u32 v = ((const u32*)outF)[i];
  h2v h = asH2(v);
  float sc = affine[512+c], sh = affine[512+128+c];
  float cand = (sc > 0.f) ? (float)h[0] : (float)h[1];
  outF[i] = fmaxf(fmaf(cand, sc, sh), 0.f);
}

// ------------------------------------------------------------- launch ----
extern "C" void kernel_launch(void* const* d_in, const int* in_sizes, int n_in,
                              void* d_out, int out_size, void* d_ws, size_t ws_size,
                              hipStream_t stream)
{
  (void)in_sizes; (void)n_in; (void)out_size; (void)ws_size;
  const float* xyz  = (const float*)d_in[0];
  const float* feat = (const float*)d_in[1];
  const float* W0 = (const float*)d_in[2];
  const float* g0 = (const float*)d_in[3];
  const float* b0 = (const float*)d_in[4];
  const float* W1 = (const float*)d_in[5];
  const float* g1 = (const float*)d_in[6];
  const float* b1 = (const float*)d_in[7];
  const float* W2 = (const float*)d_in[8];
  const float* g2 = (const float*)d_in[9];
  const float* b2 = (const float*)d_in[10];

  char* ws = (char*)d_ws;                      // 1,087,488 B total (< proven 1,088,512)
  u16*   gidx    = (u16*)  (ws + 0);           // 524288 u16  = 1048576 B
  u32*   Wf1     = (u32*)  (ws + 1048576);     // 2048 u32    =    8192 B
  u32*   Wf2     = (u32*)  (ws + 1056768);     // 2048 u32    =    8192 B
  u32*   Wf3     = (u32*)  (ws + 1064960);     // 4096 u32    =   16384 B
  float* stats   = (float*)(ws + 1081344);     // 768 f32     =    3072 B
  float* affine  = (float*)(ws + 1084416);     // 768 f32     =    3072 B

  float* out_xyz  = (float*)d_out;                         // (16,3,1024) f32
  float* out_feat = (float*)d_out + (size_t)NB*3*NS;       // (16,128,1024) f32

  prep_kernel<<<1,256,0,stream>>>(W0,W1,W2,Wf1,Wf2,Wf3,stats);
  fps_kernel<<<NB,1024,0,stream>>>(xyz, out_xyz);
  ballq_kernel<<<NB*NS/4,256,0,stream>>>(xyz, out_xyz, gidx);

  mlp_pass<0><<<NSAMP/256,256,0,stream>>>(xyz,feat,out_xyz,gidx,Wf1,Wf2,Wf3,W0,affine,stats,(u32*)out_feat);
  finalize_kernel<<<1,128,0,stream>>>(stats,     affine,     g0,b0, 64);
  mlp_pass<1><<<NSAMP/256,256,0,stream>>>(xyz,feat,out_xyz,gidx,Wf1,Wf2,Wf3,W0,affine,stats,(u32*)out_feat);
  finalize_kernel<<<1,128,0,stream>>>(stats+256, affine+256, g1,b1, 64);
  mlp_pass<2><<<NSAMP/256,256,0,stream>>>(xyz,feat,out_xyz,gidx,Wf1,Wf2,Wf3,W0,affine,stats,(u32*)out_feat);
  finalize_kernel<<<1,128,0,stream>>>(stats+512, affine+512, g2,b2, 128);
  apply_kernel<<<(NB*128*NS)/256,256,0,stream>>>(affine, out_feat);
}

// Round 14
// 1769.793 us; speedup vs baseline: 1.1460x; 1.0451x over previous
//
#include <hip/hip_runtime.h>

// PointNetSAModule on MI355X (gfx950).
// B=16, N=8192, CIN=64, S=1024, K=32, radius=0.2, MLP 67->64->64->128, eps=1e-5.
// Inputs/outputs float32 (proven R4).
//
// R13 -> R14: MLP gather de-scatter. feat is channel-major (one sample's 64
// feats span 64 cache lines). If ws_size permits (>= ~17.9 MB), transpose feat
// once to sample-major f16 (fT[n][ch], 128 B rows); MFMA B-fragments then load
// DIRECTLY from fT (16B aligned, coalesced within each row) and the LDS feat
// staging disappears. Runtime branch on ws_size: small ws -> exact R13 path.
// fps unchanged from R13 (value-only DPP reduce, 84% VALU-busy on its 16 CUs).

typedef unsigned short u16;
typedef unsigned int   u32;
typedef unsigned long long u64;

#define NB    16
#define NPTS  8192
#define CINF  64
#define NS    1024
#define KK    32
#define NSAMP (NB*NS*KK)   // 524288

typedef _Float16 h2v   __attribute__((ext_vector_type(2)));
typedef _Float16 f16x8 __attribute__((ext_vector_type(8)));
typedef float    f32x4 __attribute__((ext_vector_type(4)));
typedef float    f32x2 __attribute__((ext_vector_type(2)));

static __device__ __forceinline__ h2v asH2(u32 x){ union{u32 u; h2v h;} v; v.u=x; return v.h; }
static __device__ __forceinline__ u32 asU32(h2v h){ union{u32 u; h2v h;} v; v.h=h; return v.u; }
static __device__ __forceinline__ u32 packh(float lo, float hi){
  union{ _Float16 h[2]; u32 u; } v;
  v.h[0]=(_Float16)lo; v.h[1]=(_Float16)hi; return v.u;
}
static __device__ __forceinline__ u16 f16b(float z){
  union{ _Float16 h; u16 s; } v; v.h=(_Float16)z; return v.s;
}
static __device__ __forceinline__ f32x4 zero4(){ f32x4 z; z[0]=0.f;z[1]=0.f;z[2]=0.f;z[3]=0.f; return z; }
static __device__ __forceinline__ f16x8 zero8h(){
  f16x8 z;
  #pragma unroll
  for (int i=0;i<8;i++) z[i]=(_Float16)0.f;
  return z;
}

// exact-order d^2, matching numpy f32: (dx*dx + dy*dy) + dz*dz, no FMA contraction
static __device__ __forceinline__ float d2_exact(float ax,float ay,float az,float bx,float by,float bz){
  float dx=__fsub_rn(ax,bx), dy=__fsub_rn(ay,by), dz=__fsub_rn(az,bz);
  return __fadd_rn(__fadd_rn(__fmul_rn(dx,dx),__fmul_rn(dy,dy)),__fmul_rn(dz,dz));
}

// one DPP fmax level (VALU pipe)
template<int CTRL, int RMASK>
static __device__ __forceinline__ float dppfmax(float v){
  int o = __builtin_amdgcn_update_dpp(__float_as_int(v), __float_as_int(v),
                                      CTRL, RMASK, 0xf, false);
  return fmaxf(v, __int_as_float(o));
}

// one DPP combine level for the (kv,ki) lexicographic max (cross-wave stage only)
template<int CTRL, int RMASK>
static __device__ __forceinline__ void dppmax(u32 &kv, u32 &ki){
  u32 okv = (u32)__builtin_amdgcn_update_dpp((int)kv, (int)kv, CTRL, RMASK, 0xf, false);
  u32 oki = (u32)__builtin_amdgcn_update_dpp((int)ki, (int)ki, CTRL, RMASK, 0xf, false);
  u64 A = (((u64)okv)<<32) | oki;
  u64 B = (((u64)kv )<<32) | ki;
  if (A > B){ kv = okv; ki = oki; }
}

// ---------------------------------------------------------------- prep ----
// A-operand fragments in exact MFMA lane order: entry ((tc*2+kc)*64+lane)*4+d,
// lane m=lane&15 (channel row), q=lane>>4, k=kc*32+q*8+{2d,2d+1}.
__global__ void prep_kernel(const float* __restrict__ W0, const float* __restrict__ W1,
                            const float* __restrict__ W2,
                            u32* __restrict__ Wf1, u32* __restrict__ Wf2, u32* __restrict__ Wf3,
                            float* __restrict__ stats)
{
  const int t = threadIdx.x;
  for (int i=t;i<768;i+=256) stats[i]=0.f;
  for (int i=t;i<2048;i+=256){           // L1: 4 tiles x 2 chunks (feat cols only)
    int d=i&3, lane=(i>>2)&63, kc=(i>>8)&1, tc=i>>9;
    int row=tc*16+(lane&15), k0=kc*32+(lane>>4)*8+2*d;
    Wf1[i]=packh(W0[row*67+3+k0], W0[row*67+4+k0]);
  }
  for (int i=t;i<2048;i+=256){           // L2
    int d=i&3, lane=(i>>2)&63, kc=(i>>8)&1, tc=i>>9;
    int row=tc*16+(lane&15), k0=kc*32+(lane>>4)*8+2*d;
    Wf2[i]=packh(W1[row*64+k0], W1[row*64+k0+1]);
  }
  for (int i=t;i<4096;i+=256){           // L3
    int d=i&3, lane=(i>>2)&63, kc=(i>>8)&1, tc=i>>9;
    int row=tc*16+(lane&15), k0=kc*32+(lane>>4)*8+2*d;
    Wf3[i]=packh(W2[row*64+k0], W2[row*64+k0+1]);
  }
}

// ----------------------------------------------------- feat transpose ----
// feat (B,64,N) f32 channel-major -> fT (B*N, 64) f16 sample-major (128B rows).
// Block: one batch x 64-sample tile. Read coalesced along n; write via LDS.
__global__ __launch_bounds__(256) void transpose_kernel(const float* __restrict__ feat,
                                                        u32* __restrict__ fT32)
{
  __shared__ u16 tile[64][65];           // [ch][n], padded
  const int b  = blockIdx.x >> 7;
  const int n0 = (blockIdx.x & 127) << 6;
  const int t = threadIdx.x;
  const int ln = t & 63, lc = t >> 6;    // 4 channels per iter
  #pragma unroll
  for (int cc=0; cc<64; cc+=4){
    const int c = cc + lc;
    tile[c][ln] = f16b(feat[((size_t)b*64 + c)*NPTS + n0 + ln]);
  }
  __syncthreads();
  #pragma unroll
  for (int i=0;i<8;i++){
    const int idx = t*8 + i;             // 0..2047 = 64 rows x 32 dwords
    const int row = idx >> 5, dw = idx & 31;
    u32 pair = (u32)tile[2*dw][row] | ((u32)tile[2*dw+1][row] << 16);
    fT32[((size_t)b*NPTS + n0 + row)*32 + dw] = pair;
  }
}

// ----------------------------------------------------------------- FPS ----
// one block per batch; 1024 threads, 8 consecutive points/thread in LDS.
// Value-only DPP reduce + in-wave index recovery (R13, verified).
__global__ __launch_bounds__(1024,1) void fps_kernel(const float* __restrict__ xyz,
    float* __restrict__ out_xyz)
{
  __shared__ float sc[1024*28];            // 114,688 B
  __shared__ u32 s_kv[2][16], s_ki[2][16];
  const int b = blockIdx.x, t = threadIdx.x;
  const float* xb = xyz + (size_t)b*3*NPTS;
  const int tb = t*28;
  #pragma unroll
  for (int i=0;i<8;i++){
    const int idx = 8*t + i;
    sc[tb+i]    = xb[idx];
    sc[tb+8+i]  = xb[NPTS+idx];
    sc[tb+16+i] = xb[2*NPTS+idx];
  }
  f32x2 d[4];
  #pragma unroll
  for (int i=0;i<4;i++){ d[i][0]=__builtin_inff(); d[i][1]=__builtin_inff(); }
  __syncthreads();
  float cx = xb[0], cy = xb[NPTS], cz = xb[2*NPTS];   // initial center = point 0
  const int lane = t & 63, wv = t >> 6, l16 = lane & 15;
  for (int step=0; step<NS; step++){
    if (t==0){
      out_xyz[(size_t)(b*3+0)*NS+step]=cx;
      out_xyz[(size_t)(b*3+1)*NS+step]=cy;
      out_xyz[(size_t)(b*3+2)*NS+step]=cz;
    }
    if (step==NS-1) break;
    f32x4 X0 = *(const f32x4*)&sc[tb];
    f32x4 X1 = *(const f32x4*)&sc[tb+4];
    f32x4 Y0 = *(const f32x4*)&sc[tb+8];
    f32x4 Y1 = *(const f32x4*)&sc[tb+12];
    f32x4 Z0 = *(const f32x4*)&sc[tb+16];
    f32x4 Z1 = *(const f32x4*)&sc[tb+20];
    {
      #pragma clang fp contract(off)       // keep IEEE separate mul/add (numpy order)
      f32x2 cpx; cpx[0]=cx; cpx[1]=cx;
      f32x2 cpy; cpy[0]=cy; cpy[1]=cy;
      f32x2 cpz; cpz[0]=cz; cpz[1]=cz;
#define UPDP(pi, PX, PY, PZ) { \
      f32x2 dx = (PX) - cpx, dy = (PY) - cpy, dz = (PZ) - cpz; \
      f32x2 t1 = dx*dx; f32x2 t2 = dy*dy; f32x2 t3 = t1 + t2; \
      f32x2 t4 = dz*dz; f32x2 dd = t3 + t4; \
      d[pi] = __builtin_elementwise_min(dd, d[pi]); }
      UPDP(0, X0.lo, Y0.lo, Z0.lo)
      UPDP(1, X0.hi, Y0.hi, Z0.hi)
      UPDP(2, X1.lo, Y1.lo, Z1.lo)
      UPDP(3, X1.hi, Y1.hi, Z1.hi)
#undef UPDP
    }
    f32x2 m0 = __builtin_elementwise_max(d[0], d[1]);
    f32x2 m1 = __builtin_elementwise_max(d[2], d[3]);
    f32x2 m2 = __builtin_elementwise_max(m0, m1);
    float bv = fmaxf(m2[0], m2[1]);
    bv = dppfmax<0xB1,0xf>(bv);          // quad_perm xor1
    bv = dppfmax<0x4E,0xf>(bv);          // quad_perm xor2
    bv = dppfmax<0x141,0xf>(bv);         // row_half_mirror
    bv = dppfmax<0x140,0xf>(bv);         // row_mirror
    bv = dppfmax<0x142,0xa>(bv);         // row_bcast15
    bv = dppfmax<0x143,0xc>(bv);         // row_bcast31 -> lane 63
    const float wmax = __int_as_float(__builtin_amdgcn_readlane(__float_as_int(bv), 63));
    int ci = 8;                          // sentinel
    if (d[3][1]==wmax) ci=7;  if (d[3][0]==wmax) ci=6;
    if (d[2][1]==wmax) ci=5;  if (d[2][0]==wmax) ci=4;
    if (d[1][1]==wmax) ci=3;  if (d[1][0]==wmax) ci=2;
    if (d[0][1]==wmax) ci=1;  if (d[0][0]==wmax) ci=0;
    const int lidx = 8*t + ci;
    unsigned long long mask = __ballot(ci<8);
    const int fl = __ffsll(mask) - 1;           // first lane = smallest index
    const int widx_wave = __builtin_amdgcn_readlane(lidx, fl);
    const int p = step&1;                // double-buffered -> single barrier/step
    if (lane==0){
      s_kv[p][wv] = __float_as_uint(wmax);
      s_ki[p][wv] = (u32)(NPTS-1 - widx_wave);   // bigger = smaller idx
    }
    __syncthreads();
    u32 kv2 = s_kv[p][l16], ki2 = s_ki[p][l16];
    dppmax<0xB1,0xf>(kv2,ki2);
    dppmax<0x4E,0xf>(kv2,ki2);
    dppmax<0x141,0xf>(kv2,ki2);
    dppmax<0x140,0xf>(kv2,ki2);          // lanes 0..15 hold block winner
    const int widx = (NPTS-1) - (int)__builtin_amdgcn_readfirstlane((int)ki2);
    const int wb2 = (widx>>3)*28, wi = widx&7;
    cx = sc[wb2+wi]; cy = sc[wb2+8+wi]; cz = sc[wb2+16+wi];
  }
}

// ---------------------------------------------------------- ball query ----
__global__ __launch_bounds__(256) void ballq_kernel(const float* __restrict__ xyz,
    const float* __restrict__ out_xyz, u16* __restrict__ gidx)
{
  const int gid = blockIdx.x*4 + (threadIdx.x>>6);
  const int lane = threadIdx.x & 63;
  const int b = gid >> 10, s = gid & (NS-1);
  const float* xb = xyz + (size_t)b*3*NPTS;
  const float cx = out_xyz[(size_t)(b*3+0)*NS+s];
  const float cy = out_xyz[(size_t)(b*3+1)*NS+s];
  const float cz = out_xyz[(size_t)(b*3+2)*NS+s];
  u16* out = gidx + (size_t)gid*KK;
  int cnt=0, first=-1;
  for (int base=0; base<NPTS; base+=64){
    const int pidx = base + lane;
    float d2 = d2_exact(cx,cy,cz, xb[pidx], xb[NPTS+pidx], xb[2*NPTS+pidx]);
    bool within = d2 < 0.04f;
    unsigned long long m = __ballot(within);
    if (m){
      if (first<0) first = base + (__ffsll(m)-1);
      int pos = cnt + (int)__popcll(m & ((1ull<<lane)-1ull));
      if (within && pos<KK) out[pos]=(u16)pidx;
      cnt += (int)__popcll(m);
      if (cnt>=KK) break;
    }
  }
  if (first<0) first=0;
  for (int posi = cnt + lane; posi < KK; posi += 64) out[posi]=(u16)first;
}

// --------------------------------------------------------------- MLP -----
// STAGE 0: stats(y1) | 1: stats(y2) | 2: stats(y3) + (max,min) over K -> out.
// Block = 256 thr = 4 waves; 4 chunks x 64 samples; wave owns 16 samples.
// USET: L1 B-fragments loaded directly from sample-major f16 fT (no staging).
#define MFMA16(A,B,C) __builtin_amdgcn_mfma_f32_16x16x32_f16(A,B,C,0,0,0)

template<int STAGE, bool USET>
__global__ __launch_bounds__(256,2) void mlp_pass(
    const float* __restrict__ xyz, const float* __restrict__ feat,
    const float* __restrict__ out_xyz, const u16* __restrict__ gidx,
    const u16* __restrict__ fT,
    const u32* __restrict__ Wf1, const u32* __restrict__ Wf2, const u32* __restrict__ Wf3,
    const float* __restrict__ W0raw,
    const float* __restrict__ affine, float* __restrict__ stats, u32* __restrict__ outMM)
{
  constexpr int TCO = (STAGE==2)?128:64;
  __shared__ alignas(16) u32 Xs[64*48];          // 12 KB
  __shared__ float bins[2*TCO];
  __shared__ u32 mm[(STAGE==2)? 2*4*128 : 4];    // double-buffered cross-wave panel

  const int t = threadIdx.x;
  const int lane = t&63, w = t>>6, n = lane&15, q = lane>>4;
  const int j = t>>2, q4 = t&3;                  // gather role: sample j, quarter q4
  const int colbase = (w*16+n)*48;
  // XCD-affinity block swizzle (bijective on [0,2048))
  const int u_   = blockIdx.x;
  const int slot = u_ & 7, rr = u_ >> 3;
  const int bb   = slot*2 + (rr>>7);
  const int inner= rr & 127;
  if (t < 2*TCO) bins[t]=0.f;
  __syncthreads();                               // bins zero visible to all

  #pragma unroll 1
  for (int ch=0; ch<4; ch++){
    const int ssb = (bb*128 + inner)*256 + ch*64;      // chunk base (b,s,k)
    const int ss = ssb + j;
    const int b = bb;
    const int s = (ss >> 5) & (NS-1);
    const int g = ((int)gidx[ss]) & (NPTS-1);
    // ---- gather staging (skip feat part if USET) ----
    {
      u32* Xrow = &Xs[j*48];
      if constexpr (!USET){
        const float* fb = feat + (size_t)b*CINF*NPTS + g;
        #pragma unroll
        for (int m2=0;m2<8;m2++){
          float a0 = fb[(size_t)(16*q4+2*m2)*NPTS];
          float a1 = fb[(size_t)(16*q4+2*m2+1)*NPTS];
          Xrow[8*q4+m2] = packh(a0,a1);
        }
      }
      if (q4==3){
        const float* xb = xyz + (size_t)b*3*NPTS;
        float dx=__fsub_rn(xb[g],        out_xyz[(size_t)(b*3+0)*NS+s]);
        float dy=__fsub_rn(xb[NPTS+g],   out_xyz[(size_t)(b*3+1)*NS+s]);
        float dz=__fsub_rn(xb[2*NPTS+g], out_xyz[(size_t)(b*3+2)*NS+s]);
        Xrow[32]=packh(dx,dy); Xrow[33]=packh(dz,0.f);
      }
      #pragma unroll
      for (int i=34+q4;i<48;i+=4) Xrow[i]=0;
    }
    // per-lane sample row pointer for direct fT B-frag loads
    const u16* fr = nullptr;
    if constexpr (USET){
      const int gl = ((int)gidx[ssb + w*16 + n]) & (NPTS-1);
      fr = fT + ((size_t)bb*NPTS + gl)*64;
    }
    // ---- layer 1: Y1(64ch x 16smp) = W0 * X ----
    f32x4 acc[4];
    #pragma unroll
    for (int tc=0;tc<4;tc++) acc[tc]=zero4();
    #pragma unroll
    for (int kc=0;kc<2;kc++){
      f16x8 Bf;
      if constexpr (USET) Bf = *(const f16x8*)(fr + kc*32 + q*8);
      else                Bf = *(const f16x8*)&Xs[colbase + kc*16 + q*4];
      #pragma unroll
      for (int tc=0;tc<4;tc++){
        f16x8 Af = *(const f16x8*)&Wf1[((tc*2+kc)*64+lane)*4];
        acc[tc] = MFMA16(Af,Bf,acc[tc]);
      }
    }
    {  // xyz chunk: only q==0 of A nonzero (W0 cols 0..2), B dwords 32..47
      f16x8 Bf = *(const f16x8*)&Xs[colbase + 32 + q*4];
      #pragma unroll
      for (int tc=0;tc<4;tc++){
        f16x8 Af = zero8h();
        if (q==0){
          const int row = tc*16+n;
          Af[0]=(_Float16)W0raw[row*67+0];
          Af[1]=(_Float16)W0raw[row*67+1];
          Af[2]=(_Float16)W0raw[row*67+2];
        }
        acc[tc] = MFMA16(Af,Bf,acc[tc]);
      }
    }

    if constexpr (STAGE==0){
      #pragma unroll
      for (int tc=0;tc<4;tc++){
        #pragma unroll
        for (int r=0;r<4;r++){
          float s1=acc[tc][r], s2=__fmul_rn(s1,s1);
          #pragma unroll
          for (int off=1;off<16;off<<=1){ s1+=__shfl_xor(s1,off); s2+=__shfl_xor(s2,off); }
          if (n==0){ const int c=tc*16+q*4+r;
            atomicAdd(&bins[c], s1); atomicAdd(&bins[TCO+c], s2); }
        }
      }
    } else {
      // affine L1 + relu -> f16 -> X panel
      #pragma unroll
      for (int tc=0;tc<4;tc++){
        const f32x4 sc4 = *(const f32x4*)&affine[tc*16+q*4];
        const f32x4 sh4 = *(const f32x4*)&affine[128+tc*16+q*4];
        Xs[colbase + tc*8+q*2]   = packh(fmaxf(fmaf(acc[tc][0],sc4[0],sh4[0]),0.f),
                                         fmaxf(fmaf(acc[tc][1],sc4[1],sh4[1]),0.f));
        Xs[colbase + tc*8+q*2+1] = packh(fmaxf(fmaf(acc[tc][2],sc4[2],sh4[2]),0.f),
                                         fmaxf(fmaf(acc[tc][3],sc4[3],sh4[3]),0.f));
      }
      // ---- layer 2 ----
      f32x4 acc2[4];
      #pragma unroll
      for (int tc=0;tc<4;tc++) acc2[tc]=zero4();
      #pragma unroll
      for (int kc=0;kc<2;kc++){
        f16x8 Bf = *(const f16x8*)&Xs[colbase + kc*16 + q*4];
        #pragma unroll
        for (int tc=0;tc<4;tc++){
          f16x8 Af = *(const f16x8*)&Wf2[((tc*2+kc)*64+lane)*4];
          acc2[tc] = MFMA16(Af,Bf,acc2[tc]);
        }
      }
      if constexpr (STAGE==1){
        #pragma unroll
        for (int tc=0;tc<4;tc++){
          #pragma unroll
          for (int r=0;r<4;r++){
            float s1=acc2[tc][r], s2=__fmul_rn(s1,s1);
            #pragma unroll
            for (int off=1;off<16;off<<=1){ s1+=__shfl_xor(s1,off); s2+=__shfl_xor(s2,off); }
            if (n==0){ const int c=tc*16+q*4+r;
              atomicAdd(&bins[c], s1); atomicAdd(&bins[TCO+c], s2); }
          }
        }
      } else {
        #pragma unroll
        for (int tc=0;tc<4;tc++){
          const f32x4 sc4 = *(const f32x4*)&affine[256+tc*16+q*4];
          const f32x4 sh4 = *(const f32x4*)&affine[256+128+tc*16+q*4];
          Xs[colbase + tc*8+q*2]   = packh(fmaxf(fmaf(acc2[tc][0],sc4[0],sh4[0]),0.f),
                                           fmaxf(fmaf(acc2[tc][1],sc4[1],sh4[1]),0.f));
          Xs[colbase + tc*8+q*2+1] = packh(fmaxf(fmaf(acc2[tc][2],sc4[2],sh4[2]),0.f),
                                           fmaxf(fmaf(acc2[tc][3],sc4[3],sh4[3]),0.f));
        }
        // ---- layer 3 (128 ch) ----
        f32x4 acc3[8];
        #pragma unroll
        for (int tc=0;tc<8;tc++) acc3[tc]=zero4();
        #pragma unroll
        for (int kc=0;kc<2;kc++){
          f16x8 Bf = *(const f16x8*)&Xs[colbase + kc*16 + q*4];
          #pragma unroll
          for (int tc=0;tc<8;tc++){
            f16x8 Af = *(const f16x8*)&Wf3[((tc*2+kc)*64+lane)*4];
            acc3[tc] = MFMA16(Af,Bf,acc3[tc]);
          }
        }
        u32* mmb = &mm[(ch&1)*512];
        #pragma unroll
        for (int tc=0;tc<8;tc++){
          #pragma unroll
          for (int r=0;r<4;r++){
            float y=acc3[tc][r];
            float s1=y, s2=__fmul_rn(y,y);
            u32 pm = packh(y, -y);                       // (max, -min) carrier
            #pragma unroll
            for (int off=1;off<16;off<<=1){
              s1+=__shfl_xor(s1,off); s2+=__shfl_xor(s2,off);
              u32 o = (u32)__shfl_xor((int)pm,off);
              pm = asU32(__builtin_elementwise_max(asH2(pm), asH2(o)));
            }
            if (n==0){ const int c=tc*16+q*4+r;
              atomicAdd(&bins[c], s1); atomicAdd(&bins[128+c], s2);
              mmb[w*128+c]=pm; }
          }
        }
        __syncthreads();                                 // mm panel ready
        {
          const int c = t&127, gg = t>>7;                // 2 centers per chunk
          u32 a = mmb[(2*gg)*128+c], b2 = mmb[(2*gg+1)*128+c];
          h2v hm = __builtin_elementwise_max(asH2(a), asH2(b2));
          const int s0 = inner*8 + ch*2 + gg;
          outMM[((size_t)bb*128+c)*NS + s0] = packh((float)hm[0], -(float)hm[1]);
        }
      }
    }
  }

  __syncthreads();
  if (t < TCO){
    atomicAdd(&stats[STAGE*256 + 2*t],   bins[t]);
    atomicAdd(&stats[STAGE*256 + 2*t+1], bins[TCO+t]);
  }
}

// ----------------------------------------------------------- finalize ----
// affine SoA per layer: af[c]=scale, af[128+c]=shift
__global__ void finalize_kernel(const float* __restrict__ st, float* __restrict__ af,
                                const float* __restrict__ gamma, const float* __restrict__ beta, int C)
{
  int c = threadIdx.x;
  if (c < C){
    float mean = st[2*c] * (1.f/524288.f);
    float var  = fmaxf(st[2*c+1] * (1.f/524288.f) - mean*mean, 0.f);
    float rstd = 1.f / sqrtf(var + 1e-5f);
    float sc = rstd * gamma[c];
    af[c]     = sc;
    af[128+c] = beta[c] - mean*sc;
  }
}

// -------------------------------------------------------------- apply ----
__global__ void apply_kernel(const float* __restrict__ affine, float* __restrict__ outF)
{
  const int i = blockIdx.x*256 + threadIdx.x;      // 16*128*1024 elements
  const int c = (i >> 10) & 127;
  u32 v = ((const u32*)outF)[i];
  h2v h = asH2(v);
  float sc = affine[512+c], sh = affine[512+128+c];
  float cand = (sc > 0.f) ? (float)h[0] : (float)h[1];
  outF[i] = fmaxf(fmaf(cand, sc, sh), 0.f);
}

// ------------------------------------------------------------- launch ----
extern "C" void kernel_launch(void* const* d_in, const int* in_sizes, int n_in,
                              void* d_out, int out_size, void* d_ws, size_t ws_size,
                              hipStream_t stream)
{
  (void)in_sizes; (void)n_in; (void)out_size;
  const float* xyz  = (const float*)d_in[0];
  const float* feat = (const float*)d_in[1];
  const float* W0 = (const float*)d_in[2];
  const float* g0 = (const float*)d_in[3];
  const float* b0 = (const float*)d_in[4];
  const float* W1 = (const float*)d_in[5];
  const float* g1 = (const float*)d_in[6];
  const float* b1 = (const float*)d_in[7];
  const float* W2 = (const float*)d_in[8];
  const float* g2 = (const float*)d_in[9];
  const float* b2 = (const float*)d_in[10];

  char* ws = (char*)d_ws;
  const bool bigws = (ws_size >= 17864704);    // fT(16MB)+gidx(1MB)+Wf+stats+affine

  u16*   fT=nullptr; u16* gidx; u32 *Wf1,*Wf2,*Wf3; float *stats,*affine;
  if (bigws){
    fT     = (u16*)  (ws + 0);                 // 16,777,216 B
    gidx   = (u16*)  (ws + 16777216);          //  1,048,576 B
    Wf1    = (u32*)  (ws + 17825792);          //      8192 B
    Wf2    = (u32*)  (ws + 17833984);          //      8192 B
    Wf3    = (u32*)  (ws + 17842176);          //     16384 B
    stats  = (float*)(ws + 17858560);          //      3072 B
    affine = (float*)(ws + 17861632);          //      3072 B
  } else {                                     // proven-safe 1,087,488 B layout (R13)
    gidx   = (u16*)  (ws + 0);
    Wf1    = (u32*)  (ws + 1048576);
    Wf2    = (u32*)  (ws + 1056768);
    Wf3    = (u32*)  (ws + 1064960);
    stats  = (float*)(ws + 1081344);
    affine = (float*)(ws + 1084416);
  }

  float* out_xyz  = (float*)d_out;                         // (16,3,1024) f32
  float* out_feat = (float*)d_out + (size_t)NB*3*NS;       // (16,128,1024) f32

  prep_kernel<<<1,256,0,stream>>>(W0,W1,W2,Wf1,Wf2,Wf3,stats);
  if (bigws) transpose_kernel<<<2048,256,0,stream>>>(feat, (u32*)fT);
  fps_kernel<<<NB,1024,0,stream>>>(xyz, out_xyz);
  ballq_kernel<<<NB*NS/4,256,0,stream>>>(xyz, out_xyz, gidx);

  if (bigws){
    mlp_pass<0,true><<<NSAMP/256,256,0,stream>>>(xyz,feat,out_xyz,gidx,fT,Wf1,Wf2,Wf3,W0,affine,stats,(u32*)out_feat);
    finalize_kernel<<<1,128,0,stream>>>(stats,     affine,     g0,b0, 64);
    mlp_pass<1,true><<<NSAMP/256,256,0,stream>>>(xyz,feat,out_xyz,gidx,fT,Wf1,Wf2,Wf3,W0,affine,stats,(u32*)out_feat);
    finalize_kernel<<<1,128,0,stream>>>(stats+256, affine+256, g1,b1, 64);
    mlp_pass<2,true><<<NSAMP/256,256,0,stream>>>(xyz,feat,out_xyz,gidx,fT,Wf1,Wf2,Wf3,W0,affine,stats,(u32*)out_feat);
    finalize_kernel<<<1,128,0,stream>>>(stats+512, affine+512, g2,b2, 128);
  } else {
    mlp_pass<0,false><<<NSAMP/256,256,0,stream>>>(xyz,feat,out_xyz,gidx,nullptr,Wf1,Wf2,Wf3,W0,affine,stats,(u32*)out_feat);
    finalize_kernel<<<1,128,0,stream>>>(stats,     affine,     g0,b0, 64);
    mlp_pass<1,false><<<NSAMP/256,256,0,stream>>>(xyz,feat,out_xyz,gidx,nullptr,Wf1,Wf2,Wf3,W0,affine,stats,(u32*)out_feat);
    finalize_kernel<<<1,128,0,stream>>>(stats+256, affine+256, g1,b1, 64);
    mlp_pass<2,false><<<NSAMP/256,256,0,stream>>>(xyz,feat,out_xyz,gidx,nullptr,Wf1,Wf2,Wf3,W0,affine,stats,(u32*)out_feat);
    finalize_kernel<<<1,128,0,stream>>>(stats+512, affine+512, g2,b2, 128);
  }
  apply_kernel<<<(NB*128*NS)/256,256,0,stream>>>(affine, out_feat);
}

// Round 15
// 1647.754 us; speedup vs baseline: 1.2309x; 1.0741x over previous
//
#include <hip/hip_runtime.h>

// PointNetSAModule on MI355X (gfx950).
// B=16, N=8192, CIN=64, S=1024, K=32, radius=0.2, MLP 67->64->64->128, eps=1e-5.
// Inputs/outputs float32. ws >= 17.9 MB proven (R14 bigws path ran).
//
// R14 -> R15: PRUNED FPS. One-time in-LDS spatial sort (4x4x4 Morton cells);
// each wave owns 512 spatially-coherent points + exact bbox + cached
// (maxdist,idx) key. Per step a wave skips its whole update (7 LDS b128 reads
// + ~90 VALU) when bbox-lower-bound*0.999 > cached max dist -- provably a
// no-op update, so selection stays bit-exact (u64 keys, orig-idx tie-break).
// MLP path unchanged from R14 (MFMA + fT direct B-frags + XCD swizzle).

typedef unsigned short u16;
typedef unsigned int   u32;
typedef unsigned long long u64;

#define NB    16
#define NPTS  8192
#define CINF  64
#define NS    1024
#define KK    32
#define NSAMP (NB*NS*KK)   // 524288

typedef _Float16 h2v   __attribute__((ext_vector_type(2)));
typedef _Float16 f16x8 __attribute__((ext_vector_type(8)));
typedef float    f32x4 __attribute__((ext_vector_type(4)));
typedef float    f32x2 __attribute__((ext_vector_type(2)));

static __device__ __forceinline__ h2v asH2(u32 x){ union{u32 u; h2v h;} v; v.u=x; return v.h; }
static __device__ __forceinline__ u32 asU32(h2v h){ union{u32 u; h2v h;} v; v.h=h; return v.u; }
static __device__ __forceinline__ u32 packh(float lo, float hi){
  union{ _Float16 h[2]; u32 u; } v;
  v.h[0]=(_Float16)lo; v.h[1]=(_Float16)hi; return v.u;
}
static __device__ __forceinline__ u16 f16b(float z){
  union{ _Float16 h; u16 s; } v; v.h=(_Float16)z; return v.s;
}
static __device__ __forceinline__ f32x4 zero4(){ f32x4 z; z[0]=0.f;z[1]=0.f;z[2]=0.f;z[3]=0.f; return z; }
static __device__ __forceinline__ f16x8 zero8h(){
  f16x8 z;
  #pragma unroll
  for (int i=0;i<8;i++) z[i]=(_Float16)0.f;
  return z;
}

// exact-order d^2, matching numpy f32: (dx*dx + dy*dy) + dz*dz, no FMA contraction
static __device__ __forceinline__ float d2_exact(float ax,float ay,float az,float bx,float by,float bz){
  float dx=__fsub_rn(ax,bx), dy=__fsub_rn(ay,by), dz=__fsub_rn(az,bz);
  return __fadd_rn(__fadd_rn(__fmul_rn(dx,dx),__fmul_rn(dy,dy)),__fmul_rn(dz,dz));
}

// one DPP fmax/fmin level (VALU pipe)
template<int CTRL, int RMASK>
static __device__ __forceinline__ float dppfmax1(float v){
  int o = __builtin_amdgcn_update_dpp(__float_as_int(v), __float_as_int(v),
                                      CTRL, RMASK, 0xf, false);
  return fmaxf(v, __int_as_float(o));
}
template<int CTRL, int RMASK>
static __device__ __forceinline__ float dppfmin1(float v){
  int o = __builtin_amdgcn_update_dpp(__float_as_int(v), __float_as_int(v),
                                      CTRL, RMASK, 0xf, false);
  return fminf(v, __int_as_float(o));
}
#define RED6MAX(v) { v=dppfmax1<0xB1,0xf>(v); v=dppfmax1<0x4E,0xf>(v); v=dppfmax1<0x141,0xf>(v); \
                     v=dppfmax1<0x140,0xf>(v); v=dppfmax1<0x142,0xa>(v); v=dppfmax1<0x143,0xc>(v); }
#define RED6MIN(v) { v=dppfmin1<0xB1,0xf>(v); v=dppfmin1<0x4E,0xf>(v); v=dppfmin1<0x141,0xf>(v); \
                     v=dppfmin1<0x140,0xf>(v); v=dppfmin1<0x142,0xa>(v); v=dppfmin1<0x143,0xc>(v); }

// one DPP combine level for the (kv,ki) lexicographic max
template<int CTRL, int RMASK>
static __device__ __forceinline__ void dppmax(u32 &kv, u32 &ki){
  u32 okv = (u32)__builtin_amdgcn_update_dpp((int)kv, (int)kv, CTRL, RMASK, 0xf, false);
  u32 oki = (u32)__builtin_amdgcn_update_dpp((int)ki, (int)ki, CTRL, RMASK, 0xf, false);
  u64 A = (((u64)okv)<<32) | oki;
  u64 B = (((u64)kv )<<32) | ki;
  if (A > B){ kv = okv; ki = oki; }
}

// ---------------------------------------------------------------- prep ----
__global__ void prep_kernel(const float* __restrict__ W0, const float* __restrict__ W1,
                            const float* __restrict__ W2,
                            u32* __restrict__ Wf1, u32* __restrict__ Wf2, u32* __restrict__ Wf3,
                            float* __restrict__ stats)
{
  const int t = threadIdx.x;
  for (int i=t;i<768;i+=256) stats[i]=0.f;
  for (int i=t;i<2048;i+=256){           // L1: 4 tiles x 2 chunks (feat cols only)
    int d=i&3, lane=(i>>2)&63, kc=(i>>8)&1, tc=i>>9;
    int row=tc*16+(lane&15), k0=kc*32+(lane>>4)*8+2*d;
    Wf1[i]=packh(W0[row*67+3+k0], W0[row*67+4+k0]);
  }
  for (int i=t;i<2048;i+=256){           // L2
    int d=i&3, lane=(i>>2)&63, kc=(i>>8)&1, tc=i>>9;
    int row=tc*16+(lane&15), k0=kc*32+(lane>>4)*8+2*d;
    Wf2[i]=packh(W1[row*64+k0], W1[row*64+k0+1]);
  }
  for (int i=t;i<4096;i+=256){           // L3
    int d=i&3, lane=(i>>2)&63, kc=(i>>8)&1, tc=i>>9;
    int row=tc*16+(lane&15), k0=kc*32+(lane>>4)*8+2*d;
    Wf3[i]=packh(W2[row*64+k0], W2[row*64+k0+1]);
  }
}

// ----------------------------------------------------- feat transpose ----
// feat (B,64,N) f32 channel-major -> fT (B*N, 64) f16 sample-major (128B rows).
__global__ __launch_bounds__(256) void transpose_kernel(const float* __restrict__ feat,
                                                        u32* __restrict__ fT32)
{
  __shared__ u16 tile[64][65];           // [ch][n], padded
  const int b  = blockIdx.x >> 7;
  const int n0 = (blockIdx.x & 127) << 6;
  const int t = threadIdx.x;
  const int ln = t & 63, lc = t >> 6;
  #pragma unroll
  for (int cc=0; cc<64; cc+=4){
    const int c = cc + lc;
    tile[c][ln] = f16b(feat[((size_t)b*64 + c)*NPTS + n0 + ln]);
  }
  __syncthreads();
  #pragma unroll
  for (int i=0;i<8;i++){
    const int idx = t*8 + i;
    const int row = idx >> 5, dw = idx & 31;
    u32 pair = (u32)tile[2*dw][row] | ((u32)tile[2*dw+1][row] << 16);
    fT32[((size_t)b*NPTS + n0 + row)*32 + dw] = pair;
  }
}

// ----------------------------------------------------------------- FPS ----
// one block per batch; 1024 threads. In-LDS Morton sort (64 cells), wave owns
// 512 sorted points + exact bbox + cached (maxdist, key). Per step: bbox
// lower-bound test skips the whole update when provably a no-op (bit-exact).
__global__ __launch_bounds__(1024,1) void fps_kernel(const float* __restrict__ xyz,
    float* __restrict__ out_xyz)
{
  __shared__ float sc[1024*28];            // sorted coords: 8/thread x8|y8|z8|pad4
  __shared__ u16  sidx[NPTS];              // sorted slot -> orig idx
  __shared__ u32  hcnt[64], hoff[64];
  __shared__ u32 s_kv[2][16], s_ki[2][16];
  const int b = blockIdx.x, t = threadIdx.x;
  const float* xb = xyz + (size_t)b*3*NPTS;
  if (t<64) hcnt[t]=0;
  __syncthreads();
  // ---- pass 1: load (coalesced), Morton cell, histogram ----
  float lx[8], ly[8], lz[8]; int lcell[8];
  #pragma unroll
  for (int i=0;i<8;i++){
    const int idx = t + 1024*i;
    float x=xb[idx], y=xb[NPTS+idx], z=xb[2*NPTS+idx];
    lx[i]=x; ly[i]=y; lz[i]=z;
    int ix=(int)(x*4.f); ix = ix<0?0:(ix>3?3:ix);
    int iy=(int)(y*4.f); iy = iy<0?0:(iy>3?3:iy);
    int iz=(int)(z*4.f); iz = iz<0?0:(iz>3?3:iz);
    int m = (ix&1)|((iy&1)<<1)|((iz&1)<<2)|((ix&2)<<2)|((iy&2)<<3)|((iz&2)<<4);
    lcell[i]=m;
    atomicAdd(&hcnt[m],1u);
  }
  __syncthreads();
  if (t==0){ u32 s=0; for (int c=0;c<64;c++){ hoff[c]=s; s+=hcnt[c]; } }
  __syncthreads();
  // ---- scatter into sorted LDS layout ----
  #pragma unroll
  for (int i=0;i<8;i++){
    u32 pos = atomicAdd(&hoff[lcell[i]],1u);
    const int rb=(int)(pos>>3)*28+(int)(pos&7);
    sc[rb]=lx[i]; sc[rb+8]=ly[i]; sc[rb+16]=lz[i];
    sidx[pos]=(u16)(t+1024*i);
  }
  __syncthreads();
  // ---- wave bbox over its 512 sorted slots (this thread's 8) ----
  const int tb = t*28;
  float mnx,mxx,mny,mxy,mnz,mxz;
  {
    f32x4 X0=*(const f32x4*)&sc[tb],   X1=*(const f32x4*)&sc[tb+4];
    f32x4 Y0=*(const f32x4*)&sc[tb+8], Y1=*(const f32x4*)&sc[tb+12];
    f32x4 Z0=*(const f32x4*)&sc[tb+16],Z1=*(const f32x4*)&sc[tb+20];
    mnx=mxx=X0[0]; mny=mxy=Y0[0]; mnz=mxz=Z0[0];
    #pragma unroll
    for (int i=0;i<4;i++){
      mnx=fminf(mnx,fminf(X0[i],X1[i])); mxx=fmaxf(mxx,fmaxf(X0[i],X1[i]));
      mny=fminf(mny,fminf(Y0[i],Y1[i])); mxy=fmaxf(mxy,fmaxf(Y0[i],Y1[i]));
      mnz=fminf(mnz,fminf(Z0[i],Z1[i])); mxz=fmaxf(mxz,fmaxf(Z0[i],Z1[i]));
    }
  }
  RED6MIN(mnx) RED6MIN(mny) RED6MIN(mnz)
  RED6MAX(mxx) RED6MAX(mxy) RED6MAX(mxz)
  const float bx0=__int_as_float(__builtin_amdgcn_readlane(__float_as_int(mnx),63));
  const float bx1=__int_as_float(__builtin_amdgcn_readlane(__float_as_int(mxx),63));
  const float by0=__int_as_float(__builtin_amdgcn_readlane(__float_as_int(mny),63));
  const float by1=__int_as_float(__builtin_amdgcn_readlane(__float_as_int(mxy),63));
  const float bz0=__int_as_float(__builtin_amdgcn_readlane(__float_as_int(mnz),63));
  const float bz1=__int_as_float(__builtin_amdgcn_readlane(__float_as_int(mxz),63));

  f32x2 d[4];
  #pragma unroll
  for (int i=0;i<4;i++){ d[i][0]=__builtin_inff(); d[i][1]=__builtin_inff(); }
  u32 cached_kv = 0x7f800000u;           // +inf -> first step always updates
  u32 cached_ki = 0;

  float cx = xb[0], cy = xb[NPTS], cz = xb[2*NPTS];   // initial center = point 0
  const int lane = t & 63, wv = t >> 6, l16 = lane & 15;
  for (int step=0; step<NS; step++){
    if (t==0){
      out_xyz[(size_t)(b*3+0)*NS+step]=cx;
      out_xyz[(size_t)(b*3+1)*NS+step]=cy;
      out_xyz[(size_t)(b*3+2)*NS+step]=cz;
    }
    if (step==NS-1) break;
    // ---- wave-uniform prune test ----
    const float cval = __uint_as_float(cached_kv);
    float dxm = fmaxf(fmaxf(bx0-cx, cx-bx1), 0.f);
    float dym = fmaxf(fmaxf(by0-cy, cy-by1), 0.f);
    float dzm = fmaxf(fmaxf(bz0-cz, cz-bz1), 0.f);
    float lbs = ((dxm*dxm + dym*dym) + dzm*dzm) * 0.999f;   // conservative
    if (!(lbs > cval)){
      // ---- full update of this wave's 512 points ----
      f32x4 X0=*(const f32x4*)&sc[tb],   X1=*(const f32x4*)&sc[tb+4];
      f32x4 Y0=*(const f32x4*)&sc[tb+8], Y1=*(const f32x4*)&sc[tb+12];
      f32x4 Z0=*(const f32x4*)&sc[tb+16],Z1=*(const f32x4*)&sc[tb+20];
      uint4 sp = *(const uint4*)&sidx[8*t];    // 8 orig idx (u16)
      {
        #pragma clang fp contract(off)     // IEEE separate mul/add (numpy order)
        f32x2 cpx; cpx[0]=cx; cpx[1]=cx;
        f32x2 cpy; cpy[0]=cy; cpy[1]=cy;
        f32x2 cpz; cpz[0]=cz; cpz[1]=cz;
#define UPDP(pi, PX, PY, PZ) { \
        f32x2 dx = (PX) - cpx, dy = (PY) - cpy, dz = (PZ) - cpz; \
        f32x2 t1 = dx*dx; f32x2 t2 = dy*dy; f32x2 t3 = t1 + t2; \
        f32x2 t4 = dz*dz; f32x2 dd = t3 + t4; \
        d[pi] = __builtin_elementwise_min(dd, d[pi]); }
        UPDP(0, X0.lo, Y0.lo, Z0.lo)
        UPDP(1, X0.hi, Y0.hi, Z0.hi)
        UPDP(2, X1.lo, Y1.lo, Z1.lo)
        UPDP(3, X1.hi, Y1.hi, Z1.hi)
#undef UPDP
      }
      // per-point keys: kv=dist bits, ki=((8191-orig)<<13)|slot
      const u32 o0=sp.x&0xffffu, o1=sp.x>>16, o2=sp.y&0xffffu, o3=sp.y>>16;
      const u32 o4=sp.z&0xffffu, o5=sp.z>>16, o6=sp.w&0xffffu, o7=sp.w>>16;
      u32 bkv = __float_as_uint(d[0][0]);
      u32 bki = ((8191u-o0)<<13) | (u32)(8*t+0);
#define KUPD(val, orig, ii) { \
      u32 kv = __float_as_uint(val); \
      u32 ki = ((8191u-(orig))<<13) | (u32)(8*t+(ii)); \
      u64 A = (((u64)kv)<<32)|ki, Bq = (((u64)bkv)<<32)|bki; \
      if (A > Bq){ bkv=kv; bki=ki; } }
      KUPD(d[0][1], o1, 1) KUPD(d[1][0], o2, 2) KUPD(d[1][1], o3, 3)
      KUPD(d[2][0], o4, 4) KUPD(d[2][1], o5, 5) KUPD(d[3][0], o6, 6)
      KUPD(d[3][1], o7, 7)
#undef KUPD
      dppmax<0xB1,0xf>(bkv,bki);
      dppmax<0x4E,0xf>(bkv,bki);
      dppmax<0x141,0xf>(bkv,bki);
      dppmax<0x140,0xf>(bkv,bki);
      dppmax<0x142,0xa>(bkv,bki);
      dppmax<0x143,0xc>(bkv,bki);          // lane 63 has wave winner
      cached_kv = (u32)__builtin_amdgcn_readlane((int)bkv, 63);
      cached_ki = (u32)__builtin_amdgcn_readlane((int)bki, 63);
    }
    const int p = step&1;                  // single barrier per step
    if (lane==0){ s_kv[p][wv]=cached_kv; s_ki[p][wv]=cached_ki; }
    __syncthreads();
    u32 kv2 = s_kv[p][l16], ki2 = s_ki[p][l16];
    dppmax<0xB1,0xf>(kv2,ki2);
    dppmax<0x4E,0xf>(kv2,ki2);
    dppmax<0x141,0xf>(kv2,ki2);
    dppmax<0x140,0xf>(kv2,ki2);            // lanes 0..15 hold block winner
    const int wslot = (int)((u32)__builtin_amdgcn_readfirstlane((int)ki2) & 8191u);
    const int wb2 = (wslot>>3)*28, wi = wslot&7;
    cx = sc[wb2+wi]; cy = sc[wb2+8+wi]; cz = sc[wb2+16+wi];
  }
}

// ---------------------------------------------------------- ball query ----
__global__ __launch_bounds__(256) void ballq_kernel(const float* __restrict__ xyz,
    const float* __restrict__ out_xyz, u16* __restrict__ gidx)
{
  const int gid = blockIdx.x*4 + (threadIdx.x>>6);
  const int lane = threadIdx.x & 63;
  const int b = gid >> 10, s = gid & (NS-1);
  const float* xb = xyz + (size_t)b*3*NPTS;
  const float cx = out_xyz[(size_t)(b*3+0)*NS+s];
  const float cy = out_xyz[(size_t)(b*3+1)*NS+s];
  const float cz = out_xyz[(size_t)(b*3+2)*NS+s];
  u16* out = gidx + (size_t)gid*KK;
  int cnt=0, first=-1;
  for (int base=0; base<NPTS; base+=64){
    const int pidx = base + lane;
    float d2 = d2_exact(cx,cy,cz, xb[pidx], xb[NPTS+pidx], xb[2*NPTS+pidx]);
    bool within = d2 < 0.04f;
    unsigned long long m = __ballot(within);
    if (m){
      if (first<0) first = base + (__ffsll(m)-1);
      int pos = cnt + (int)__popcll(m & ((1ull<<lane)-1ull));
      if (within && pos<KK) out[pos]=(u16)pidx;
      cnt += (int)__popcll(m);
      if (cnt>=KK) break;
    }
  }
  if (first<0) first=0;
  for (int posi = cnt + lane; posi < KK; posi += 64) out[posi]=(u16)first;
}

// --------------------------------------------------------------- MLP -----
#define MFMA16(A,B,C) __builtin_amdgcn_mfma_f32_16x16x32_f16(A,B,C,0,0,0)

template<int STAGE>
__global__ __launch_bounds__(256,2) void mlp_pass(
    const float* __restrict__ xyz, const float* __restrict__ feat,
    const float* __restrict__ out_xyz, const u16* __restrict__ gidx,
    const u16* __restrict__ fT,
    const u32* __restrict__ Wf1, const u32* __restrict__ Wf2, const u32* __restrict__ Wf3,
    const float* __restrict__ W0raw,
    const float* __restrict__ affine, float* __restrict__ stats, u32* __restrict__ outMM)
{
  constexpr int TCO = (STAGE==2)?128:64;
  __shared__ alignas(16) u32 Xs[64*48];          // 12 KB
  __shared__ float bins[2*TCO];
  __shared__ u32 mm[(STAGE==2)? 2*4*128 : 4];    // double-buffered cross-wave panel

  const int t = threadIdx.x;
  const int lane = t&63, w = t>>6, n = lane&15, q = lane>>4;
  const int j = t>>2, q4 = t&3;
  const int colbase = (w*16+n)*48;
  const int u_   = blockIdx.x;                   // XCD-affinity swizzle
  const int slot = u_ & 7, rr = u_ >> 3;
  const int bb   = slot*2 + (rr>>7);
  const int inner= rr & 127;
  if (t < 2*TCO) bins[t]=0.f;
  __syncthreads();

  #pragma unroll 1
  for (int ch=0; ch<4; ch++){
    const int ssb = (bb*128 + inner)*256 + ch*64;
    const int ss = ssb + j;
    const int s = (ss >> 5) & (NS-1);
    const int g = ((int)gidx[ss]) & (NPTS-1);
    {
      u32* Xrow = &Xs[j*48];
      if (q4==3){
        const float* xb = xyz + (size_t)bb*3*NPTS;
        float dx=__fsub_rn(xb[g],        out_xyz[(size_t)(bb*3+0)*NS+s]);
        float dy=__fsub_rn(xb[NPTS+g],   out_xyz[(size_t)(bb*3+1)*NS+s]);
        float dz=__fsub_rn(xb[2*NPTS+g], out_xyz[(size_t)(bb*3+2)*NS+s]);
        Xrow[32]=packh(dx,dy); Xrow[33]=packh(dz,0.f);
      }
      #pragma unroll
      for (int i=34+q4;i<48;i+=4) Xrow[i]=0;
    }
    const u16* fr;
    {
      const int gl = ((int)gidx[ssb + w*16 + n]) & (NPTS-1);
      fr = fT + ((size_t)bb*NPTS + gl)*64;
    }
    // ---- layer 1 ----
    f32x4 acc[4];
    #pragma unroll
    for (int tc=0;tc<4;tc++) acc[tc]=zero4();
    #pragma unroll
    for (int kc=0;kc<2;kc++){
      f16x8 Bf = *(const f16x8*)(fr + kc*32 + q*8);
      #pragma unroll
      for (int tc=0;tc<4;tc++){
        f16x8 Af = *(const f16x8*)&Wf1[((tc*2+kc)*64+lane)*4];
        acc[tc] = MFMA16(Af,Bf,acc[tc]);
      }
    }
    {  // xyz chunk
      f16x8 Bf = *(const f16x8*)&Xs[colbase + 32 + q*4];
      #pragma unroll
      for (int tc=0;tc<4;tc++){
        f16x8 Af = zero8h();
        if (q==0){
          const int row = tc*16+n;
          Af[0]=(_Float16)W0raw[row*67+0];
          Af[1]=(_Float16)W0raw[row*67+1];
          Af[2]=(_Float16)W0raw[row*67+2];
        }
        acc[tc] = MFMA16(Af,Bf,acc[tc]);
      }
    }

    if constexpr (STAGE==0){
      #pragma unroll
      for (int tc=0;tc<4;tc++){
        #pragma unroll
        for (int r=0;r<4;r++){
          float s1=acc[tc][r], s2=__fmul_rn(s1,s1);
          #pragma unroll
          for (int off=1;off<16;off<<=1){ s1+=__shfl_xor(s1,off); s2+=__shfl_xor(s2,off); }
          if (n==0){ const int c=tc*16+q*4+r;
            atomicAdd(&bins[c], s1); atomicAdd(&bins[TCO+c], s2); }
        }
      }
    } else {
      #pragma unroll
      for (int tc=0;tc<4;tc++){
        const f32x4 sc4 = *(const f32x4*)&affine[tc*16+q*4];
        const f32x4 sh4 = *(const f32x4*)&affine[128+tc*16+q*4];
        Xs[colbase + tc*8+q*2]   = packh(fmaxf(fmaf(acc[tc][0],sc4[0],sh4[0]),0.f),
                                         fmaxf(fmaf(acc[tc][1],sc4[1],sh4[1]),0.f));
        Xs[colbase + tc*8+q*2+1] = packh(fmaxf(fmaf(acc[tc][2],sc4[2],sh4[2]),0.f),
                                         fmaxf(fmaf(acc[tc][3],sc4[3],sh4[3]),0.f));
      }
      // ---- layer 2 ----
      f32x4 acc2[4];
      #pragma unroll
      for (int tc=0;tc<4;tc++) acc2[tc]=zero4();
      #pragma unroll
      for (int kc=0;kc<2;kc++){
        f16x8 Bf = *(const f16x8*)&Xs[colbase + kc*16 + q*4];
        #pragma unroll
        for (int tc=0;tc<4;tc++){
          f16x8 Af = *(const f16x8*)&Wf2[((tc*2+kc)*64+lane)*4];
          acc2[tc] = MFMA16(Af,Bf,acc2[tc]);
        }
      }
      if constexpr (STAGE==1){
        #pragma unroll
        for (int tc=0;tc<4;tc++){
          #pragma unroll
          for (int r=0;r<4;r++){
            float s1=acc2[tc][r], s2=__fmul_rn(s1,s1);
            #pragma unroll
            for (int off=1;off<16;off<<=1){ s1+=__shfl_xor(s1,off); s2+=__shfl_xor(s2,off); }
            if (n==0){ const int c=tc*16+q*4+r;
              atomicAdd(&bins[c], s1); atomicAdd(&bins[TCO+c], s2); }
          }
        }
      } else {
        #pragma unroll
        for (int tc=0;tc<4;tc++){
          const f32x4 sc4 = *(const f32x4*)&affine[256+tc*16+q*4];
          const f32x4 sh4 = *(const f32x4*)&affine[256+128+tc*16+q*4];
          Xs[colbase + tc*8+q*2]   = packh(fmaxf(fmaf(acc2[tc][0],sc4[0],sh4[0]),0.f),
                                           fmaxf(fmaf(acc2[tc][1],sc4[1],sh4[1]),0.f));
          Xs[colbase + tc*8+q*2+1] = packh(fmaxf(fmaf(acc2[tc][2],sc4[2],sh4[2]),0.f),
                                           fmaxf(fmaf(acc2[tc][3],sc4[3],sh4[3]),0.f));
        }
        // ---- layer 3 ----
        f32x4 acc3[8];
        #pragma unroll
        for (int tc=0;tc<8;tc++) acc3[tc]=zero4();
        #pragma unroll
        for (int kc=0;kc<2;kc++){
          f16x8 Bf = *(const f16x8*)&Xs[colbase + kc*16 + q*4];
          #pragma unroll
          for (int tc=0;tc<8;tc++){
            f16x8 Af = *(const f16x8*)&Wf3[((tc*2+kc)*64+lane)*4];
            acc3[tc] = MFMA16(Af,Bf,acc3[tc]);
          }
        }
        u32* mmb = &mm[(ch&1)*512];
        #pragma unroll
        for (int tc=0;tc<8;tc++){
          #pragma unroll
          for (int r=0;r<4;r++){
            float y=acc3[tc][r];
            float s1=y, s2=__fmul_rn(y,y);
            u32 pm = packh(y, -y);
            #pragma unroll
            for (int off=1;off<16;off<<=1){
              s1+=__shfl_xor(s1,off); s2+=__shfl_xor(s2,off);
              u32 o = (u32)__shfl_xor((int)pm,off);
              pm = asU32(__builtin_elementwise_max(asH2(pm), asH2(o)));
            }
            if (n==0){ const int c=tc*16+q*4+r;
              atomicAdd(&bins[c], s1); atomicAdd(&bins[128+c], s2);
              mmb[w*128+c]=pm; }
          }
        }
        __syncthreads();
        {
          const int c = t&127, gg = t>>7;
          u32 a = mmb[(2*gg)*128+c], b2 = mmb[(2*gg+1)*128+c];
          h2v hm = __builtin_elementwise_max(asH2(a), asH2(b2));
          const int s0 = inner*8 + ch*2 + gg;
          outMM[((size_t)bb*128+c)*NS + s0] = packh((float)hm[0], -(float)hm[1]);
        }
      }
    }
  }

  __syncthreads();
  if (t < TCO){
    atomicAdd(&stats[STAGE*256 + 2*t],   bins[t]);
    atomicAdd(&stats[STAGE*256 + 2*t+1], bins[TCO+t]);
  }
}

// ----------------------------------------------------------- finalize ----
__global__ void finalize_kernel(const float* __restrict__ st, float* __restrict__ af,
                                const float* __restrict__ gamma, const float* __restrict__ beta, int C)
{
  int c = threadIdx.x;
  if (c < C){
    float mean = st[2*c] * (1.f/524288.f);
    float var  = fmaxf(st[2*c+1] * (1.f/524288.f) - mean*mean, 0.f);
    float rstd = 1.f / sqrtf(var + 1e-5f);
    float sc = rstd * gamma[c];
    af[c]     = sc;
    af[128+c] = beta[c] - mean*sc;
  }
}

// -------------------------------------------------------------- apply ----
__global__ void apply_kernel(const float* __restrict__ affine, float* __restrict__ outF)
{
  const int i = blockIdx.x*256 + threadIdx.x;
  const int c = (i >> 10) & 127;
  u32 v = ((const u32*)outF)[i];
  h2v h = asH2(v);
  float sc = affine[512+c], sh = affine[512+128+c];
  float cand = (sc > 0.f) ? (float)h[0] : (float)h[1];
  outF[i] = fmaxf(fmaf(cand, sc, sh), 0.f);
}

// ------------------------------------------------------------- launch ----
extern "C" void kernel_launch(void* const* d_in, const int* in_sizes, int n_in,
                              void* d_out, int out_size, void* d_ws, size_t ws_size,
                              hipStream_t stream)
{
  (void)in_sizes; (void)n_in; (void)out_size; (void)ws_size;
  const float* xyz  = (const float*)d_in[0];
  const float* feat = (const float*)d_in[1];
  const float* W0 = (const float*)d_in[2];
  const float* g0 = (const float*)d_in[3];
  const float* b0 = (const float*)d_in[4];
  const float* W1 = (const float*)d_in[5];
  const float* g1 = (const float*)d_in[6];
  const float* b1 = (const float*)d_in[7];
  const float* W2 = (const float*)d_in[8];
  const float* g2 = (const float*)d_in[9];
  const float* b2 = (const float*)d_in[10];

  char* ws = (char*)d_ws;                       // 17,864,704 B (proven R14)
  u16*   fT     = (u16*)  (ws + 0);             // 16,777,216 B
  u16*   gidx   = (u16*)  (ws + 16777216);      //  1,048,576 B
  u32*   Wf1    = (u32*)  (ws + 17825792);      //      8192 B
  u32*   Wf2    = (u32*)  (ws + 17833984);      //      8192 B
  u32*   Wf3    = (u32*)  (ws + 17842176);      //     16384 B
  float* stats  = (float*)(ws + 17858560);      //      3072 B
  float* affine = (float*)(ws + 17861632);      //      3072 B

  float* out_xyz  = (float*)d_out;                         // (16,3,1024) f32
  float* out_feat = (float*)d_out + (size_t)NB*3*NS;       // (16,128,1024) f32

  prep_kernel<<<1,256,0,stream>>>(W0,W1,W2,Wf1,Wf2,Wf3,stats);
  transpose_kernel<<<2048,256,0,stream>>>(feat, (u32*)fT);
  fps_kernel<<<NB,1024,0,stream>>>(xyz, out_xyz);
  ballq_kernel<<<NB*NS/4,256,0,stream>>>(xyz, out_xyz, gidx);

  mlp_pass<0><<<NSAMP/256,256,0,stream>>>(xyz,feat,out_xyz,gidx,fT,Wf1,Wf2,Wf3,W0,affine,stats,(u32*)out_feat);
  finalize_kernel<<<1,128,0,stream>>>(stats,     affine,     g0,b0, 64);
  mlp_pass<1><<<NSAMP/256,256,0,stream>>>(xyz,feat,out_xyz,gidx,fT,Wf1,Wf2,Wf3,W0,affine,stats,(u32*)out_feat);
  finalize_kernel<<<1,128,0,stream>>>(stats+256, affine+256, g1,b1, 64);
  mlp_pass<2><<<NSAMP/256,256,0,stream>>>(xyz,feat,out_xyz,gidx,fT,Wf1,Wf2,Wf3,W0,affine,stats,(u32*)out_feat);
  finalize_kernel<<<1,128,0,stream>>>(stats+512, affine+512, g2,b2, 128);
  apply_kernel<<<(NB*128*NS)/256,256,0,stream>>>(affine, out_feat);
}

// Round 16
// 1613.514 us; speedup vs baseline: 1.2570x; 1.0212x over previous
//
#include <hip/hip_runtime.h>

// PointNetSAModule on MI355X (gfx950).
// B=16, N=8192, CIN=64, S=1024, K=32, radius=0.2, MLP 67->64->64->128, eps=1e-5.
// Inputs/outputs float32. ws >= 17.9 MB proven (R14).
//
// R15 -> R16: fps update body slimmed. Keeps R15's Morton-sort + wave-bbox
// prune (skip = provable no-op) but replaces the per-point u64 key chain with
// R13's value-only reduce + match recovery: 6 DPP fmax -> wmax, then matched
// keys (precomputed (8192-orig)<<13|slot, hoisted out of the loop) reduced by
// 6 u32 DPP v_max_u32 levels. Exact numpy first-argmax semantics preserved
// (ties -> smallest orig; cross-wave stage still u64 lexicographic).
// MLP path unchanged from R15.

typedef unsigned short u16;
typedef unsigned int   u32;
typedef unsigned long long u64;

#define NB    16
#define NPTS  8192
#define CINF  64
#define NS    1024
#define KK    32
#define NSAMP (NB*NS*KK)   // 524288

typedef _Float16 h2v   __attribute__((ext_vector_type(2)));
typedef _Float16 f16x8 __attribute__((ext_vector_type(8)));
typedef float    f32x4 __attribute__((ext_vector_type(4)));
typedef float    f32x2 __attribute__((ext_vector_type(2)));

static __device__ __forceinline__ h2v asH2(u32 x){ union{u32 u; h2v h;} v; v.u=x; return v.h; }
static __device__ __forceinline__ u32 asU32(h2v h){ union{u32 u; h2v h;} v; v.h=h; return v.u; }
static __device__ __forceinline__ u32 packh(float lo, float hi){
  union{ _Float16 h[2]; u32 u; } v;
  v.h[0]=(_Float16)lo; v.h[1]=(_Float16)hi; return v.u;
}
static __device__ __forceinline__ u16 f16b(float z){
  union{ _Float16 h; u16 s; } v; v.h=(_Float16)z; return v.s;
}
static __device__ __forceinline__ f32x4 zero4(){ f32x4 z; z[0]=0.f;z[1]=0.f;z[2]=0.f;z[3]=0.f; return z; }
static __device__ __forceinline__ f16x8 zero8h(){
  f16x8 z;
  #pragma unroll
  for (int i=0;i<8;i++) z[i]=(_Float16)0.f;
  return z;
}

// exact-order d^2, matching numpy f32: (dx*dx + dy*dy) + dz*dz, no FMA contraction
static __device__ __forceinline__ float d2_exact(float ax,float ay,float az,float bx,float by,float bz){
  float dx=__fsub_rn(ax,bx), dy=__fsub_rn(ay,by), dz=__fsub_rn(az,bz);
  return __fadd_rn(__fadd_rn(__fmul_rn(dx,dx),__fmul_rn(dy,dy)),__fmul_rn(dz,dz));
}

// DPP helpers (VALU pipe)
template<int CTRL, int RMASK>
static __device__ __forceinline__ float dppfmax1(float v){
  int o = __builtin_amdgcn_update_dpp(__float_as_int(v), __float_as_int(v),
                                      CTRL, RMASK, 0xf, false);
  return fmaxf(v, __int_as_float(o));
}
template<int CTRL, int RMASK>
static __device__ __forceinline__ float dppfmin1(float v){
  int o = __builtin_amdgcn_update_dpp(__float_as_int(v), __float_as_int(v),
                                      CTRL, RMASK, 0xf, false);
  return fminf(v, __int_as_float(o));
}
template<int CTRL, int RMASK>
static __device__ __forceinline__ u32 dppumax1(u32 v){
  u32 o = (u32)__builtin_amdgcn_update_dpp((int)v, (int)v, CTRL, RMASK, 0xf, false);
  return v > o ? v : o;
}
#define RED6MAX(v) { v=dppfmax1<0xB1,0xf>(v); v=dppfmax1<0x4E,0xf>(v); v=dppfmax1<0x141,0xf>(v); \
                     v=dppfmax1<0x140,0xf>(v); v=dppfmax1<0x142,0xa>(v); v=dppfmax1<0x143,0xc>(v); }
#define RED6MIN(v) { v=dppfmin1<0xB1,0xf>(v); v=dppfmin1<0x4E,0xf>(v); v=dppfmin1<0x141,0xf>(v); \
                     v=dppfmin1<0x140,0xf>(v); v=dppfmin1<0x142,0xa>(v); v=dppfmin1<0x143,0xc>(v); }
#define RED6UMAX(v) { v=dppumax1<0xB1,0xf>(v); v=dppumax1<0x4E,0xf>(v); v=dppumax1<0x141,0xf>(v); \
                      v=dppumax1<0x140,0xf>(v); v=dppumax1<0x142,0xa>(v); v=dppumax1<0x143,0xc>(v); }

// one DPP combine level for the (kv,ki) lexicographic max (cross-wave stage)
template<int CTRL, int RMASK>
static __device__ __forceinline__ void dppmax(u32 &kv, u32 &ki){
  u32 okv = (u32)__builtin_amdgcn_update_dpp((int)kv, (int)kv, CTRL, RMASK, 0xf, false);
  u32 oki = (u32)__builtin_amdgcn_update_dpp((int)ki, (int)ki, CTRL, RMASK, 0xf, false);
  u64 A = (((u64)okv)<<32) | oki;
  u64 B = (((u64)kv )<<32) | ki;
  if (A > B){ kv = okv; ki = oki; }
}

// ---------------------------------------------------------------- prep ----
__global__ void prep_kernel(const float* __restrict__ W0, const float* __restrict__ W1,
                            const float* __restrict__ W2,
                            u32* __restrict__ Wf1, u32* __restrict__ Wf2, u32* __restrict__ Wf3,
                            float* __restrict__ stats)
{
  const int t = threadIdx.x;
  for (int i=t;i<768;i+=256) stats[i]=0.f;
  for (int i=t;i<2048;i+=256){           // L1: 4 tiles x 2 chunks (feat cols only)
    int d=i&3, lane=(i>>2)&63, kc=(i>>8)&1, tc=i>>9;
    int row=tc*16+(lane&15), k0=kc*32+(lane>>4)*8+2*d;
    Wf1[i]=packh(W0[row*67+3+k0], W0[row*67+4+k0]);
  }
  for (int i=t;i<2048;i+=256){           // L2
    int d=i&3, lane=(i>>2)&63, kc=(i>>8)&1, tc=i>>9;
    int row=tc*16+(lane&15), k0=kc*32+(lane>>4)*8+2*d;
    Wf2[i]=packh(W1[row*64+k0], W1[row*64+k0+1]);
  }
  for (int i=t;i<4096;i+=256){           // L3
    int d=i&3, lane=(i>>2)&63, kc=(i>>8)&1, tc=i>>9;
    int row=tc*16+(lane&15), k0=kc*32+(lane>>4)*8+2*d;
    Wf3[i]=packh(W2[row*64+k0], W2[row*64+k0+1]);
  }
}

// ----------------------------------------------------- feat transpose ----
__global__ __launch_bounds__(256) void transpose_kernel(const float* __restrict__ feat,
                                                        u32* __restrict__ fT32)
{
  __shared__ u16 tile[64][65];
  const int b  = blockIdx.x >> 7;
  const int n0 = (blockIdx.x & 127) << 6;
  const int t = threadIdx.x;
  const int ln = t & 63, lc = t >> 6;
  #pragma unroll
  for (int cc=0; cc<64; cc+=4){
    const int c = cc + lc;
    tile[c][ln] = f16b(feat[((size_t)b*64 + c)*NPTS + n0 + ln]);
  }
  __syncthreads();
  #pragma unroll
  for (int i=0;i<8;i++){
    const int idx = t*8 + i;
    const int row = idx >> 5, dw = idx & 31;
    u32 pair = (u32)tile[2*dw][row] | ((u32)tile[2*dw+1][row] << 16);
    fT32[((size_t)b*NPTS + n0 + row)*32 + dw] = pair;
  }
}

// ----------------------------------------------------------------- FPS ----
// one block per batch; 1024 threads. Morton sort -> wave-compact regions,
// wave bbox prune (no-op skip), value-only DPP reduce + matched-key recovery.
__global__ __launch_bounds__(1024,1) void fps_kernel(const float* __restrict__ xyz,
    float* __restrict__ out_xyz)
{
  __shared__ float sc[1024*28];            // sorted coords: 8/thread x8|y8|z8|pad4
  __shared__ u16  sidx[NPTS];              // sorted slot -> orig idx
  __shared__ u32  hcnt[64], hoff[64];
  __shared__ u32 s_kv[2][16], s_ki[2][16];
  const int b = blockIdx.x, t = threadIdx.x;
  const float* xb = xyz + (size_t)b*3*NPTS;
  if (t<64) hcnt[t]=0;
  __syncthreads();
  // ---- pass 1: load (coalesced), Morton cell, histogram ----
  float lx[8], ly[8], lz[8]; int lcell[8];
  #pragma unroll
  for (int i=0;i<8;i++){
    const int idx = t + 1024*i;
    float x=xb[idx], y=xb[NPTS+idx], z=xb[2*NPTS+idx];
    lx[i]=x; ly[i]=y; lz[i]=z;
    int ix=(int)(x*4.f); ix = ix<0?0:(ix>3?3:ix);
    int iy=(int)(y*4.f); iy = iy<0?0:(iy>3?3:iy);
    int iz=(int)(z*4.f); iz = iz<0?0:(iz>3?3:iz);
    int m = (ix&1)|((iy&1)<<1)|((iz&1)<<2)|((ix&2)<<2)|((iy&2)<<3)|((iz&2)<<4);
    lcell[i]=m;
    atomicAdd(&hcnt[m],1u);
  }
  __syncthreads();
  if (t==0){ u32 s=0; for (int c=0;c<64;c++){ hoff[c]=s; s+=hcnt[c]; } }
  __syncthreads();
  // ---- scatter into sorted LDS layout ----
  #pragma unroll
  for (int i=0;i<8;i++){
    u32 pos = atomicAdd(&hoff[lcell[i]],1u);
    const int rb=(int)(pos>>3)*28+(int)(pos&7);
    sc[rb]=lx[i]; sc[rb+8]=ly[i]; sc[rb+16]=lz[i];
    sidx[pos]=(u16)(t+1024*i);
  }
  __syncthreads();
  // ---- wave bbox + hoisted per-point key constants ----
  const int tb = t*28;
  float mnx,mxx,mny,mxy,mnz,mxz;
  {
    f32x4 X0=*(const f32x4*)&sc[tb],   X1=*(const f32x4*)&sc[tb+4];
    f32x4 Y0=*(const f32x4*)&sc[tb+8], Y1=*(const f32x4*)&sc[tb+12];
    f32x4 Z0=*(const f32x4*)&sc[tb+16],Z1=*(const f32x4*)&sc[tb+20];
    mnx=mxx=X0[0]; mny=mxy=Y0[0]; mnz=mxz=Z0[0];
    #pragma unroll
    for (int i=0;i<4;i++){
      mnx=fminf(mnx,fminf(X0[i],X1[i])); mxx=fmaxf(mxx,fmaxf(X0[i],X1[i]));
      mny=fminf(mny,fminf(Y0[i],Y1[i])); mxy=fmaxf(mxy,fmaxf(Y0[i],Y1[i]));
      mnz=fminf(mnz,fminf(Z0[i],Z1[i])); mxz=fmaxf(mxz,fmaxf(Z0[i],Z1[i]));
    }
  }
  RED6MIN(mnx) RED6MIN(mny) RED6MIN(mnz)
  RED6MAX(mxx) RED6MAX(mxy) RED6MAX(mxz)
  const float bx0=__int_as_float(__builtin_amdgcn_readlane(__float_as_int(mnx),63));
  const float bx1=__int_as_float(__builtin_amdgcn_readlane(__float_as_int(mxx),63));
  const float by0=__int_as_float(__builtin_amdgcn_readlane(__float_as_int(mny),63));
  const float by1=__int_as_float(__builtin_amdgcn_readlane(__float_as_int(mxy),63));
  const float bz0=__int_as_float(__builtin_amdgcn_readlane(__float_as_int(mnz),63));
  const float bz1=__int_as_float(__builtin_amdgcn_readlane(__float_as_int(mxz),63));
  // hoisted: key constants (8192-orig)<<13 | slot  (>= 1<<13 > 0 always)
  u32 kb[8];
  {
    uint4 sp = *(const uint4*)&sidx[8*t];
    const u32 o0=sp.x&0xffffu, o1=sp.x>>16, o2=sp.y&0xffffu, o3=sp.y>>16;
    const u32 o4=sp.z&0xffffu, o5=sp.z>>16, o6=sp.w&0xffffu, o7=sp.w>>16;
    kb[0]=((8192u-o0)<<13)|(u32)(8*t+0); kb[1]=((8192u-o1)<<13)|(u32)(8*t+1);
    kb[2]=((8192u-o2)<<13)|(u32)(8*t+2); kb[3]=((8192u-o3)<<13)|(u32)(8*t+3);
    kb[4]=((8192u-o4)<<13)|(u32)(8*t+4); kb[5]=((8192u-o5)<<13)|(u32)(8*t+5);
    kb[6]=((8192u-o6)<<13)|(u32)(8*t+6); kb[7]=((8192u-o7)<<13)|(u32)(8*t+7);
  }

  f32x2 d[4];
  #pragma unroll
  for (int i=0;i<4;i++){ d[i][0]=__builtin_inff(); d[i][1]=__builtin_inff(); }
  u32 cached_kv = 0x7f800000u;           // +inf -> first step always updates
  u32 cached_ki = 0;

  float cx = xb[0], cy = xb[NPTS], cz = xb[2*NPTS];   // initial center = point 0
  const int lane = t & 63, wv = t >> 6, l16 = lane & 15;
  for (int step=0; step<NS; step++){
    if (t==0){
      out_xyz[(size_t)(b*3+0)*NS+step]=cx;
      out_xyz[(size_t)(b*3+1)*NS+step]=cy;
      out_xyz[(size_t)(b*3+2)*NS+step]=cz;
    }
    if (step==NS-1) break;
    // ---- wave-uniform prune test ----
    const float cval = __uint_as_float(cached_kv);
    float dxm = fmaxf(fmaxf(bx0-cx, cx-bx1), 0.f);
    float dym = fmaxf(fmaxf(by0-cy, cy-by1), 0.f);
    float dzm = fmaxf(fmaxf(bz0-cz, cz-bz1), 0.f);
    float lbs = ((dxm*dxm + dym*dym) + dzm*dzm) * 0.999f;   // conservative
    if (!(lbs > cval)){
      // ---- full update of this wave's 512 points ----
      f32x4 X0=*(const f32x4*)&sc[tb],   X1=*(const f32x4*)&sc[tb+4];
      f32x4 Y0=*(const f32x4*)&sc[tb+8], Y1=*(const f32x4*)&sc[tb+12];
      f32x4 Z0=*(const f32x4*)&sc[tb+16],Z1=*(const f32x4*)&sc[tb+20];
      {
        #pragma clang fp contract(off)     // IEEE separate mul/add (numpy order)
        f32x2 cpx; cpx[0]=cx; cpx[1]=cx;
        f32x2 cpy; cpy[0]=cy; cpy[1]=cy;
        f32x2 cpz; cpz[0]=cz; cpz[1]=cz;
#define UPDP(pi, PX, PY, PZ) { \
        f32x2 dx = (PX) - cpx, dy = (PY) - cpy, dz = (PZ) - cpz; \
        f32x2 t1 = dx*dx; f32x2 t2 = dy*dy; f32x2 t3 = t1 + t2; \
        f32x2 t4 = dz*dz; f32x2 dd = t3 + t4; \
        d[pi] = __builtin_elementwise_min(dd, d[pi]); }
        UPDP(0, X0.lo, Y0.lo, Z0.lo)
        UPDP(1, X0.hi, Y0.hi, Z0.hi)
        UPDP(2, X1.lo, Y1.lo, Z1.lo)
        UPDP(3, X1.hi, Y1.hi, Z1.hi)
#undef UPDP
      }
      // value-only wave max
      f32x2 m0 = __builtin_elementwise_max(d[0], d[1]);
      f32x2 m1 = __builtin_elementwise_max(d[2], d[3]);
      f32x2 m2 = __builtin_elementwise_max(m0, m1);
      float bv = fmaxf(m2[0], m2[1]);
      RED6MAX(bv)                          // lane 63 valid
      const float wmax = __int_as_float(__builtin_amdgcn_readlane(__float_as_int(bv), 63));
      // matched-key recovery: max key among points with d == wmax (exact bits)
      u32 ki = 0;
      if (d[0][0]==wmax) ki = kb[0];
      if (d[0][1]==wmax && kb[1]>ki) ki = kb[1];
      if (d[1][0]==wmax && kb[2]>ki) ki = kb[2];
      if (d[1][1]==wmax && kb[3]>ki) ki = kb[3];
      if (d[2][0]==wmax && kb[4]>ki) ki = kb[4];
      if (d[2][1]==wmax && kb[5]>ki) ki = kb[5];
      if (d[3][0]==wmax && kb[6]>ki) ki = kb[6];
      if (d[3][1]==wmax && kb[7]>ki) ki = kb[7];
      RED6UMAX(ki)                         // lane 63: max key = smallest orig
      cached_kv = (u32)__builtin_amdgcn_readlane(__float_as_int(wmax), 0) ?
                  __float_as_uint(wmax) : __float_as_uint(wmax);   // SGPR already
      cached_kv = __float_as_uint(wmax);
      cached_ki = (u32)__builtin_amdgcn_readlane((int)ki, 63);
    }
    const int p = step&1;                  // single barrier per step
    if (lane==0){ s_kv[p][wv]=cached_kv; s_ki[p][wv]=cached_ki; }
    __syncthreads();
    u32 kv2 = s_kv[p][l16], ki2 = s_ki[p][l16];
    dppmax<0xB1,0xf>(kv2,ki2);
    dppmax<0x4E,0xf>(kv2,ki2);
    dppmax<0x141,0xf>(kv2,ki2);
    dppmax<0x140,0xf>(kv2,ki2);            // lanes 0..15 hold block winner
    const int wslot = (int)((u32)__builtin_amdgcn_readfirstlane((int)ki2) & 8191u);
    const int wb2 = (wslot>>3)*28, wi = wslot&7;
    cx = sc[wb2+wi]; cy = sc[wb2+8+wi]; cz = sc[wb2+16+wi];
  }
}

// ---------------------------------------------------------- ball query ----
__global__ __launch_bounds__(256) void ballq_kernel(const float* __restrict__ xyz,
    const float* __restrict__ out_xyz, u16* __restrict__ gidx)
{
  const int gid = blockIdx.x*4 + (threadIdx.x>>6);
  const int lane = threadIdx.x & 63;
  const int b = gid >> 10, s = gid & (NS-1);
  const float* xb = xyz + (size_t)b*3*NPTS;
  const float cx = out_xyz[(size_t)(b*3+0)*NS+s];
  const float cy = out_xyz[(size_t)(b*3+1)*NS+s];
  const float cz = out_xyz[(size_t)(b*3+2)*NS+s];
  u16* out = gidx + (size_t)gid*KK;
  int cnt=0, first=-1;
  for (int base=0; base<NPTS; base+=64){
    const int pidx = base + lane;
    float d2 = d2_exact(cx,cy,cz, xb[pidx], xb[NPTS+pidx], xb[2*NPTS+pidx]);
    bool within = d2 < 0.04f;
    unsigned long long m = __ballot(within);
    if (m){
      if (first<0) first = base + (__ffsll(m)-1);
      int pos = cnt + (int)__popcll(m & ((1ull<<lane)-1ull));
      if (within && pos<KK) out[pos]=(u16)pidx;
      cnt += (int)__popcll(m);
      if (cnt>=KK) break;
    }
  }
  if (first<0) first=0;
  for (int posi = cnt + lane; posi < KK; posi += 64) out[posi]=(u16)first;
}

// --------------------------------------------------------------- MLP -----
#define MFMA16(A,B,C) __builtin_amdgcn_mfma_f32_16x16x32_f16(A,B,C,0,0,0)

template<int STAGE>
__global__ __launch_bounds__(256,2) void mlp_pass(
    const float* __restrict__ xyz, const float* __restrict__ feat,
    const float* __restrict__ out_xyz, const u16* __restrict__ gidx,
    const u16* __restrict__ fT,
    const u32* __restrict__ Wf1, const u32* __restrict__ Wf2, const u32* __restrict__ Wf3,
    const float* __restrict__ W0raw,
    const float* __restrict__ affine, float* __restrict__ stats, u32* __restrict__ outMM)
{
  constexpr int TCO = (STAGE==2)?128:64;
  __shared__ alignas(16) u32 Xs[64*48];          // 12 KB
  __shared__ float bins[2*TCO];
  __shared__ u32 mm[(STAGE==2)? 2*4*128 : 4];    // double-buffered cross-wave panel

  const int t = threadIdx.x;
  const int lane = t&63, w = t>>6, n = lane&15, q = lane>>4;
  const int j = t>>2, q4 = t&3;
  const int colbase = (w*16+n)*48;
  const int u_   = blockIdx.x;                   // XCD-affinity swizzle
  const int slot = u_ & 7, rr = u_ >> 3;
  const int bb   = slot*2 + (rr>>7);
  const int inner= rr & 127;
  if (t < 2*TCO) bins[t]=0.f;
  __syncthreads();

  #pragma unroll 1
  for (int ch=0; ch<4; ch++){
    const int ssb = (bb*128 + inner)*256 + ch*64;
    const int ss = ssb + j;
    const int s = (ss >> 5) & (NS-1);
    const int g = ((int)gidx[ss]) & (NPTS-1);
    {
      u32* Xrow = &Xs[j*48];
      if (q4==3){
        const float* xb = xyz + (size_t)bb*3*NPTS;
        float dx=__fsub_rn(xb[g],        out_xyz[(size_t)(bb*3+0)*NS+s]);
        float dy=__fsub_rn(xb[NPTS+g],   out_xyz[(size_t)(bb*3+1)*NS+s]);
        float dz=__fsub_rn(xb[2*NPTS+g], out_xyz[(size_t)(bb*3+2)*NS+s]);
        Xrow[32]=packh(dx,dy); Xrow[33]=packh(dz,0.f);
      }
      #pragma unroll
      for (int i=34+q4;i<48;i+=4) Xrow[i]=0;
    }
    const u16* fr;
    {
      const int gl = ((int)gidx[ssb + w*16 + n]) & (NPTS-1);
      fr = fT + ((size_t)bb*NPTS + gl)*64;
    }
    // ---- layer 1 ----
    f32x4 acc[4];
    #pragma unroll
    for (int tc=0;tc<4;tc++) acc[tc]=zero4();
    #pragma unroll
    for (int kc=0;kc<2;kc++){
      f16x8 Bf = *(const f16x8*)(fr + kc*32 + q*8);
      #pragma unroll
      for (int tc=0;tc<4;tc++){
        f16x8 Af = *(const f16x8*)&Wf1[((tc*2+kc)*64+lane)*4];
        acc[tc] = MFMA16(Af,Bf,acc[tc]);
      }
    }
    {  // xyz chunk
      f16x8 Bf = *(const f16x8*)&Xs[colbase + 32 + q*4];
      #pragma unroll
      for (int tc=0;tc<4;tc++){
        f16x8 Af = zero8h();
        if (q==0){
          const int row = tc*16+n;
          Af[0]=(_Float16)W0raw[row*67+0];
          Af[1]=(_Float16)W0raw[row*67+1];
          Af[2]=(_Float16)W0raw[row*67+2];
        }
        acc[tc] = MFMA16(Af,Bf,acc[tc]);
      }
    }

    if constexpr (STAGE==0){
      #pragma unroll
      for (int tc=0;tc<4;tc++){
        #pragma unroll
        for (int r=0;r<4;r++){
          float s1=acc[tc][r], s2=__fmul_rn(s1,s1);
          #pragma unroll
          for (int off=1;off<16;off<<=1){ s1+=__shfl_xor(s1,off); s2+=__shfl_xor(s2,off); }
          if (n==0){ const int c=tc*16+q*4+r;
            atomicAdd(&bins[c], s1); atomicAdd(&bins[TCO+c], s2); }
        }
      }
    } else {
      #pragma unroll
      for (int tc=0;tc<4;tc++){
        const f32x4 sc4 = *(const f32x4*)&affine[tc*16+q*4];
        const f32x4 sh4 = *(const f32x4*)&affine[128+tc*16+q*4];
        Xs[colbase + tc*8+q*2]   = packh(fmaxf(fmaf(acc[tc][0],sc4[0],sh4[0]),0.f),
                                         fmaxf(fmaf(acc[tc][1],sc4[1],sh4[1]),0.f));
        Xs[colbase + tc*8+q*2+1] = packh(fmaxf(fmaf(acc[tc][2],sc4[2],sh4[2]),0.f),
                                         fmaxf(fmaf(acc[tc][3],sc4[3],sh4[3]),0.f));
      }
      // ---- layer 2 ----
      f32x4 acc2[4];
      #pragma unroll
      for (int tc=0;tc<4;tc++) acc2[tc]=zero4();
      #pragma unroll
      for (int kc=0;kc<2;kc++){
        f16x8 Bf = *(const f16x8*)&Xs[colbase + kc*16 + q*4];
        #pragma unroll
        for (int tc=0;tc<4;tc++){
          f16x8 Af = *(const f16x8*)&Wf2[((tc*2+kc)*64+lane)*4];
          acc2[tc] = MFMA16(Af,Bf,acc2[tc]);
        }
      }
      if constexpr (STAGE==1){
        #pragma unroll
        for (int tc=0;tc<4;tc++){
          #pragma unroll
          for (int r=0;r<4;r++){
            float s1=acc2[tc][r], s2=__fmul_rn(s1,s1);
            #pragma unroll
            for (int off=1;off<16;off<<=1){ s1+=__shfl_xor(s1,off); s2+=__shfl_xor(s2,off); }
            if (n==0){ const int c=tc*16+q*4+r;
              atomicAdd(&bins[c], s1); atomicAdd(&bins[TCO+c], s2); }
          }
        }
      } else {
        #pragma unroll
        for (int tc=0;tc<4;tc++){
          const f32x4 sc4 = *(const f32x4*)&affine[256+tc*16+q*4];
          const f32x4 sh4 = *(const f32x4*)&affine[256+128+tc*16+q*4];
          Xs[colbase + tc*8+q*2]   = packh(fmaxf(fmaf(acc2[tc][0],sc4[0],sh4[0]),0.f),
                                           fmaxf(fmaf(acc2[tc][1],sc4[1],sh4[1]),0.f));
          Xs[colbase + tc*8+q*2+1] = packh(fmaxf(fmaf(acc2[tc][2],sc4[2],sh4[2]),0.f),
                                           fmaxf(fmaf(acc2[tc][3],sc4[3],sh4[3]),0.f));
        }
        // ---- layer 3 ----
        f32x4 acc3[8];
        #pragma unroll
        for (int tc=0;tc<8;tc++) acc3[tc]=zero4();
        #pragma unroll
        for (int kc=0;kc<2;kc++){
          f16x8 Bf = *(const f16x8*)&Xs[colbase + kc*16 + q*4];
          #pragma unroll
          for (int tc=0;tc<8;tc++){
            f16x8 Af = *(const f16x8*)&Wf3[((tc*2+kc)*64+lane)*4];
            acc3[tc] = MFMA16(Af,Bf,acc3[tc]);
          }
        }
        u32* mmb = &mm[(ch&1)*512];
        #pragma unroll
        for (int tc=0;tc<8;tc++){
          #pragma unroll
          for (int r=0;r<4;r++){
            float y=acc3[tc][r];
            float s1=y, s2=__fmul_rn(y,y);
            u32 pm = packh(y, -y);
            #pragma unroll
            for (int off=1;off<16;off<<=1){
              s1+=__shfl_xor(s1,off); s2+=__shfl_xor(s2,off);
              u32 o = (u32)__shfl_xor((int)pm,off);
              pm = asU32(__builtin_elementwise_max(asH2(pm), asH2(o)));
            }
            if (n==0){ const int c=tc*16+q*4+r;
              atomicAdd(&bins[c], s1); atomicAdd(&bins[128+c], s2);
              mmb[w*128+c]=pm; }
          }
        }
        __syncthreads();
        {
          const int c = t&127, gg = t>>7;
          u32 a = mmb[(2*gg)*128+c], b2 = mmb[(2*gg+1)*128+c];
          h2v hm = __builtin_elementwise_max(asH2(a), asH2(b2));
          const int s0 = inner*8 + ch*2 + gg;
          outMM[((size_t)bb*128+c)*NS + s0] = packh((float)hm[0], -(float)hm[1]);
        }
      }
    }
  }

  __syncthreads();
  if (t < TCO){
    atomicAdd(&stats[STAGE*256 + 2*t],   bins[t]);
    atomicAdd(&stats[STAGE*256 + 2*t+1], bins[TCO+t]);
  }
}

// ----------------------------------------------------------- finalize ----
__global__ void finalize_kernel(const float* __restrict__ st, float* __restrict__ af,
                                const float* __restrict__ gamma, const float* __restrict__ beta, int C)
{
  int c = threadIdx.x;
  if (c < C){
    float mean = st[2*c] * (1.f/524288.f);
    float var  = fmaxf(st[2*c+1] * (1.f/524288.f) - mean*mean, 0.f);
    float rstd = 1.f / sqrtf(var + 1e-5f);
    float sc = rstd * gamma[c];
    af[c]     = sc;
    af[128+c] = beta[c] - mean*sc;
  }
}

// -------------------------------------------------------------- apply ----
__global__ void apply_kernel(const float* __restrict__ affine, float* __restrict__ outF)
{
  const int i = blockIdx.x*256 + threadIdx.x;
  const int c = (i >> 10) & 127;
  u32 v = ((const u32*)outF)[i];
  h2v h = asH2(v);
  float sc = affine[512+c], sh = affine[512+128+c];
  float cand = (sc > 0.f) ? (float)h[0] : (float)h[1];
  outF[i] = fmaxf(fmaf(cand, sc, sh), 0.f);
}

// ------------------------------------------------------------- launch ----
extern "C" void kernel_launch(void* const* d_in, const int* in_sizes, int n_in,
                              void* d_out, int out_size, void* d_ws, size_t ws_size,
                              hipStream_t stream)
{
  (void)in_sizes; (void)n_in; (void)out_size; (void)ws_size;
  const float* xyz  = (const float*)d_in[0];
  const float* feat = (const float*)d_in[1];
  const float* W0 = (const float*)d_in[2];
  const float* g0 = (const float*)d_in[3];
  const float* b0 = (const float*)d_in[4];
  const float* W1 = (const float*)d_in[5];
  const float* g1 = (const float*)d_in[6];
  const float* b1 = (const float*)d_in[7];
  const float* W2 = (const float*)d_in[8];
  const float* g2 = (const float*)d_in[9];
  const float* b2 = (const float*)d_in[10];

  char* ws = (char*)d_ws;                       // 17,864,704 B (proven R14)
  u16*   fT     = (u16*)  (ws + 0);             // 16,777,216 B
  u16*   gidx   = (u16*)  (ws + 16777216);      //  1,048,576 B
  u32*   Wf1    = (u32*)  (ws + 17825792);      //      8192 B
  u32*   Wf2    = (u32*)  (ws + 17833984);      //      8192 B
  u32*   Wf3    = (u32*)  (ws + 17842176);      //     16384 B
  float* stats  = (float*)(ws + 17858560);      //      3072 B
  float* affine = (float*)(ws + 17861632);      //      3072 B

  float* out_xyz  = (float*)d_out;                         // (16,3,1024) f32
  float* out_feat = (float*)d_out + (size_t)NB*3*NS;       // (16,128,1024) f32

  prep_kernel<<<1,256,0,stream>>>(W0,W1,W2,Wf1,Wf2,Wf3,stats);
  transpose_kernel<<<2048,256,0,stream>>>(feat, (u32*)fT);
  fps_kernel<<<NB,1024,0,stream>>>(xyz, out_xyz);
  ballq_kernel<<<NB*NS/4,256,0,stream>>>(xyz, out_xyz, gidx);

  mlp_pass<0><<<NSAMP/256,256,0,stream>>>(xyz,feat,out_xyz,gidx,fT,Wf1,Wf2,Wf3,W0,affine,stats,(u32*)out_feat);
  finalize_kernel<<<1,128,0,stream>>>(stats,     affine,     g0,b0, 64);
  mlp_pass<1><<<NSAMP/256,256,0,stream>>>(xyz,feat,out_xyz,gidx,fT,Wf1,Wf2,Wf3,W0,affine,stats,(u32*)out_feat);
  finalize_kernel<<<1,128,0,stream>>>(stats+256, affine+256, g1,b1, 64);
  mlp_pass<2><<<NSAMP/256,256,0,stream>>>(xyz,feat,out_xyz,gidx,fT,Wf1,Wf2,Wf3,W0,affine,stats,(u32*)out_feat);
  finalize_kernel<<<1,128,0,stream>>>(stats+512, affine+512, g2,b2, 128);
  apply_kernel<<<(NB*128*NS)/256,256,0,stream>>>(affine, out_feat);
}